// Round 6
// baseline (443.458 us; speedup 1.0000x reference)
//
#include <hip/hip_runtime.h>
#include <hip/hip_bf16.h>

typedef __bf16 bf16x8 __attribute__((ext_vector_type(8)));
typedef __bf16 bf16x4 __attribute__((ext_vector_type(4)));
typedef float f32x4 __attribute__((ext_vector_type(4)));

#define T_SEQ 2048
#define EMB 1024
#define NH 16
#define DV 64

// async global->LDS, 16B per lane (wave-uniform LDS base + lane*16 layout required)
__device__ __forceinline__ void gload16(const __bf16* g, __bf16* l) {
    __builtin_amdgcn_global_load_lds(
        (const __attribute__((address_space(1))) unsigned int*)g,
        (__attribute__((address_space(3))) unsigned int*)l, 16, 0, 0);
}

// ---------------- transpose + fp32->bf16 convert (with scale) ----------------
__global__ void transpose_cvt(const float* __restrict__ src, __bf16* __restrict__ dst,
                              int R, int C, long src_bstride, long dst_bstride, float scale) {
    __shared__ float tile[32][33];
    const int b = blockIdx.z;
    const float* s = src + (long)b * src_bstride;
    __bf16* d = dst + (long)b * dst_bstride;
    const int c0 = blockIdx.x * 32, r0 = blockIdx.y * 32;
    #pragma unroll
    for (int i = threadIdx.y; i < 32; i += 8)
        tile[i][threadIdx.x] = s[(long)(r0 + i) * C + c0 + threadIdx.x];
    __syncthreads();
    #pragma unroll
    for (int i = threadIdx.y; i < 32; i += 8)
        d[(long)(c0 + i) * R + r0 + threadIdx.x] = (__bf16)(tile[threadIdx.x][i] * scale);
}

// ---------------- V transpose: qkv -> Vt[bh][64][2048] ----------------
__global__ void vt_transpose(const __bf16* __restrict__ qkv, __bf16* __restrict__ Vt) {
    __shared__ __bf16 tile[64][72];
    const int bh = blockIdx.y, b = bh >> 4, h = bh & 15;
    const int t0 = blockIdx.x * 64;
    const __bf16* src = qkv + (long)b * T_SEQ * 3072 + 2048 + h * 64;
    const int tt = threadIdx.x >> 3, seg = threadIdx.x & 7;
    #pragma unroll
    for (int half = 0; half < 2; half++) {
        const int t = half * 32 + tt;
        bf16x8 v = *reinterpret_cast<const bf16x8*>(src + (long)(t0 + t) * 3072 + seg * 8);
        *reinterpret_cast<bf16x8*>(&tile[t][seg * 8]) = v;
    }
    __syncthreads();
    __bf16* dst = Vt + (long)bh * 64 * T_SEQ + t0;
    #pragma unroll
    for (int half = 0; half < 2; half++) {
        const int d = half * 32 + tt;
        bf16x8 v;
        #pragma unroll
        for (int i = 0; i < 8; i++) v[i] = tile[seg * 8 + i][d];
        *reinterpret_cast<bf16x8*>(dst + (long)d * T_SEQ + seg * 8) = v;
    }
}

// ---------------- LayerNorm: fp32 in -> bf16 out ----------------
__global__ void ln_kernel(const float* __restrict__ x, const float* __restrict__ g,
                          const float* __restrict__ be, __bf16* __restrict__ out) {
    const int row = blockIdx.x;
    const float4 xv = reinterpret_cast<const float4*>(x + (long)row * EMB)[threadIdx.x];
    float s = xv.x + xv.y + xv.z + xv.w;
    float sq = xv.x * xv.x + xv.y * xv.y + xv.z * xv.z + xv.w * xv.w;
    #pragma unroll
    for (int off = 32; off; off >>= 1) { s += __shfl_down(s, off); sq += __shfl_down(sq, off); }
    __shared__ float red[8];
    const int w = threadIdx.x >> 6, lane = threadIdx.x & 63;
    if (lane == 0) { red[w] = s; red[4 + w] = sq; }
    __syncthreads();
    if (threadIdx.x == 0) {
        float st = red[0] + red[1] + red[2] + red[3];
        float sqt = red[4] + red[5] + red[6] + red[7];
        float mean = st * (1.0f / EMB);
        float var = sqt * (1.0f / EMB) - mean * mean;
        red[0] = mean; red[1] = rsqrtf(var + 1e-5f);
    }
    __syncthreads();
    const float mean = red[0], rstd = red[1];
    const float4 gv = reinterpret_cast<const float4*>(g)[threadIdx.x];
    const float4 bv = reinterpret_cast<const float4*>(be)[threadIdx.x];
    bf16x4 o;
    o[0] = (__bf16)((xv.x - mean) * rstd * gv.x + bv.x);
    o[1] = (__bf16)((xv.y - mean) * rstd * gv.y + bv.y);
    o[2] = (__bf16)((xv.z - mean) * rstd * gv.z + bv.z);
    o[3] = (__bf16)((xv.w - mean) * rstd * gv.w + bv.w);
    *reinterpret_cast<bf16x4*>(out + (long)row * EMB + threadIdx.x * 4) = o;
}

// ---------------- bf16 GEMM (NT), m97 structure ----------------
// C[M][N] = A[M][K] * BT[N][K]^T. 128xBN tile, BK=64, global_load_lds staging,
// linear LDS, 2 barriers per K-step. 4 waves 2x2; wave tile 64 x BN/2.
template <int BN, int OUT_BF16, int RELU, int HAS_BIAS, int HAS_RES>
__global__ __launch_bounds__(256)
void gemm_nt(const __bf16* __restrict__ A, const __bf16* __restrict__ BT,
             const float* __restrict__ bias, const float* __restrict__ res,
             void* __restrict__ outp, int M, int N, int K) {
    constexpr int NFN = BN / 32;                 // 16-wide n-frags per wave
    __shared__ __align__(16) __bf16 As[128 * 64];
    __shared__ __align__(16) __bf16 Bs[BN * 64];
    const int t = threadIdx.x;
    const int w = t >> 6, lane = t & 63;
    const int wm = (w >> 1) * 64, wn = (w & 1) * (BN / 2);
    const int m0 = blockIdx.y * 128, n0 = blockIdx.x * BN;
    const int rA = lane & 15, kA = (lane >> 4) * 8;
    const int srow = t >> 3;                     // 0..31
    const int scol = (t & 7) * 8;                // element offset (16B chunks)

    const __bf16* Ab = A + (long)(m0 + srow) * K + scol;
    const __bf16* Bb = BT + (long)(n0 + srow) * K + scol;
    __bf16* Asw = As + srow * 64 + scol;
    __bf16* Bsw = Bs + srow * 64 + scol;

    f32x4 acc[4][NFN] = {};
    for (int k0 = 0; k0 < K; k0 += 64) {
        #pragma unroll
        for (int i = 0; i < 4; i++)
            gload16(Ab + (long)(32 * i) * K + k0, Asw + 32 * i * 64);
        #pragma unroll
        for (int i = 0; i < BN / 32; i++)
            gload16(Bb + (long)(32 * i) * K + k0, Bsw + 32 * i * 64);
        __syncthreads();   // compiler drains vmcnt before barrier
        #pragma unroll
        for (int kk = 0; kk < 2; kk++) {
            bf16x8 af[4], bfr[NFN];
            #pragma unroll
            for (int m = 0; m < 4; m++)
                af[m] = *reinterpret_cast<const bf16x8*>(As + (wm + m * 16 + rA) * 64 + kk * 32 + kA);
            #pragma unroll
            for (int n = 0; n < NFN; n++)
                bfr[n] = *reinterpret_cast<const bf16x8*>(Bs + (wn + n * 16 + rA) * 64 + kk * 32 + kA);
            #pragma unroll
            for (int m = 0; m < 4; m++)
                #pragma unroll
                for (int n = 0; n < NFN; n++)
                    acc[m][n] = __builtin_amdgcn_mfma_f32_16x16x32_bf16(af[m], bfr[n], acc[m][n], 0, 0, 0);
        }
        __syncthreads();
    }
    const int rl = (lane >> 4) * 4, cl = lane & 15;
    #pragma unroll
    for (int m = 0; m < 4; m++) {
        #pragma unroll
        for (int n = 0; n < NFN; n++) {
            const int gc = n0 + wn + n * 16 + cl;
            float bval = 0.0f;
            if (HAS_BIAS) bval = bias[gc];
            #pragma unroll
            for (int r = 0; r < 4; r++) {
                const int gr = m0 + wm + m * 16 + rl + r;
                float v = acc[m][n][r] + bval;
                if (HAS_RES) v += res[(long)gr * N + gc];
                if (RELU) v = fmaxf(v, 0.0f);
                if (OUT_BF16) ((__bf16*)outp)[(long)gr * N + gc] = (__bf16)v;
                else          ((float*)outp)[(long)gr * N + gc] = v;
            }
        }
    }
}

// ---------------- causal flash attention: LDS-staged, double-buffered ----------------
// K LDS tile: logical [64 kv][128B d], phys byte = row*128 + (col ^ ((row&7)<<4))
// V LDS tile: logical [64 d][128B kv], same swizzle.
template <int MASKED>
__device__ __forceinline__ void attn_compute(
    const char* __restrict__ Kl, const char* __restrict__ Vl,
    __bf16 (*__restrict__ PsW)[72],
    const bf16x8 (&qf)[2][2], const bf16x8& ones,
    f32x4 (&o)[2][4], f32x4 (&l5)[2], float (&mr)[2][4],
    int kv0, int rA, int g, int rl, int qw)
{
    const int swz = (rA & 7) << 4;
    bf16x8 kf[4][2];
    #pragma unroll
    for (int c = 0; c < 4; c++)
        #pragma unroll
        for (int kc = 0; kc < 2; kc++)
            kf[c][kc] = *reinterpret_cast<const bf16x8*>(
                Kl + (c * 16 + rA) * 128 + ((kc * 64 + g * 16) ^ swz));
    f32x4 sa[2][4];
    #pragma unroll
    for (int rt = 0; rt < 2; rt++)
        #pragma unroll
        for (int c = 0; c < 4; c++) {
            f32x4 acc = {};
            acc = __builtin_amdgcn_mfma_f32_16x16x32_bf16(qf[rt][0], kf[c][0], acc, 0, 0, 0);
            acc = __builtin_amdgcn_mfma_f32_16x16x32_bf16(qf[rt][1], kf[c][1], acc, 0, 0, 0);
            sa[rt][c] = acc;
        }
    #pragma unroll
    for (int rt = 0; rt < 2; rt++) {
        #pragma unroll
        for (int r = 0; r < 4; r++) {
            float s0 = sa[rt][0][r], s1 = sa[rt][1][r], s2 = sa[rt][2][r], s3 = sa[rt][3][r];
            if (MASKED) {
                const int gr = qw + rt * 16 + rl + r;
                if (kv0 + rA > gr)      s0 = -__builtin_inff();
                if (kv0 + 16 + rA > gr) s1 = -__builtin_inff();
                if (kv0 + 32 + rA > gr) s2 = -__builtin_inff();
                if (kv0 + 48 + rA > gr) s3 = -__builtin_inff();
            }
            float tm = fmaxf(fmaxf(s0, s1), fmaxf(s2, s3));
            #pragma unroll
            for (int msk = 1; msk < 16; msk <<= 1) tm = fmaxf(tm, __shfl_xor(tm, msk));
            const float mo = mr[rt][r];
            const float mn = fmaxf(mo, tm);
            mr[rt][r] = mn;
            const float sc = __expf(mo - mn);
            const float p0 = __expf(s0 - mn);
            const float p1 = __expf(s1 - mn);
            const float p2 = __expf(s2 - mn);
            const float p3 = __expf(s3 - mn);
            #pragma unroll
            for (int n = 0; n < 4; n++) o[rt][n][r] *= sc;
            l5[rt][r] *= sc;
            const int prow = rt * 16 + rl + r;
            PsW[prow][rA]      = (__bf16)p0;
            PsW[prow][16 + rA] = (__bf16)p1;
            PsW[prow][32 + rA] = (__bf16)p2;
            PsW[prow][48 + rA] = (__bf16)p3;
        }
    }
    asm volatile("s_waitcnt lgkmcnt(0)" ::: "memory");

    bf16x8 ap[2][2];
    #pragma unroll
    for (int rt = 0; rt < 2; rt++)
        #pragma unroll
        for (int ks = 0; ks < 2; ks++)
            ap[rt][ks] = *reinterpret_cast<const bf16x8*>(&PsW[rt * 16 + rA][ks * 32 + g * 8]);
    #pragma unroll
    for (int ks = 0; ks < 2; ks++) {
        #pragma unroll
        for (int rt = 0; rt < 2; rt++)
            l5[rt] = __builtin_amdgcn_mfma_f32_16x16x32_bf16(ap[rt][ks], ones, l5[rt], 0, 0, 0);
        #pragma unroll
        for (int n = 0; n < 4; n++) {
            bf16x8 bv = *reinterpret_cast<const bf16x8*>(
                Vl + (n * 16 + rA) * 128 + ((ks * 64 + g * 16) ^ swz));
            #pragma unroll
            for (int rt = 0; rt < 2; rt++)
                o[rt][n] = __builtin_amdgcn_mfma_f32_16x16x32_bf16(ap[rt][ks], bv, o[rt][n], 0, 0, 0);
        }
    }
}

__global__ __launch_bounds__(256)
void attn_kernel(const __bf16* __restrict__ qkv, const __bf16* __restrict__ Vt,
                 __bf16* __restrict__ attn) {
    __shared__ __bf16 Ks[2][64 * 64];
    __shared__ __bf16 Vs[2][64 * 64];
    __shared__ __bf16 Ps[4][32][72];

    const int bh = blockIdx.y, b = bh >> 4, h = bh & 15;
    const int qtile = (int)gridDim.x - 1 - (int)blockIdx.x;
    const int q0 = qtile * 128;
    const int w = threadIdx.x >> 6, lane = threadIdx.x & 63;
    const int qw = q0 + w * 32;
    const int rA = lane & 15, g = lane >> 4, rl = g * 4;
    const int srow8 = lane >> 3;
    const int scol = (lane & 7) * 16;
    const int wcol = scol ^ (srow8 << 4);

    const char* qb = (const char*)(qkv + (long)b * T_SEQ * 3072 + h * 64);
    const char* kb = qb + 2048;
    const char* vtb = (const char*)(Vt + (long)bh * 64 * T_SEQ);

    bf16x8 qf[2][2];
    #pragma unroll
    for (int rt = 0; rt < 2; rt++)
        #pragma unroll
        for (int kc = 0; kc < 2; kc++)
            qf[rt][kc] = *reinterpret_cast<const bf16x8*>(
                qb + (long)(qw + rt * 16 + rA) * 6144 + kc * 64 + g * 16);

    bf16x8 ones;
    #pragma unroll
    for (int i = 0; i < 8; i++) ones[i] = (__bf16)1.0f;

    f32x4 o[2][4] = {};
    f32x4 l5[2] = {};
    float mr[2][4];
    #pragma unroll
    for (int rt = 0; rt < 2; rt++)
        #pragma unroll
        for (int r = 0; r < 4; r++) mr[rt][r] = -__builtin_inff();

    const int nsteps = q0 / 64 + 2;
    const int t_avail = qw + 32;
    const int isK = (w < 2);
    const int r0 = (w & 1) * 32 + srow8;

    bf16x8 stg[4];
    auto issue = [&](int kv0) {
        if (isK) {
            #pragma unroll
            for (int i = 0; i < 4; i++)
                stg[i] = *reinterpret_cast<const bf16x8*>(kb + (long)(kv0 + r0 + i * 8) * 6144 + scol);
        } else {
            #pragma unroll
            for (int i = 0; i < 4; i++)
                stg[i] = *reinterpret_cast<const bf16x8*>(vtb + (long)(r0 + i * 8) * 4096 + kv0 * 2 + scol);
        }
    };
    auto lwrite = [&](int buf) {
        char* base = isK ? (char*)Ks[buf] : (char*)Vs[buf];
        #pragma unroll
        for (int i = 0; i < 4; i++)
            *reinterpret_cast<bf16x8*>(base + (r0 + i * 8) * 128 + wcol) = stg[i];
    };

    issue(0);
    lwrite(0);
    __syncthreads();

    for (int t = 0; t < nsteps; ++t) {
        const int kv0 = t * 64, cur = t & 1;
        const bool has_next = (t + 1 < nsteps);
        if (has_next) issue(kv0 + 64);
        if (kv0 < t_avail) {
            if (kv0 + 64 <= qw)
                attn_compute<0>((const char*)Ks[cur], (const char*)Vs[cur], Ps[w],
                                qf, ones, o, l5, mr, kv0, rA, g, rl, qw);
            else
                attn_compute<1>((const char*)Ks[cur], (const char*)Vs[cur], Ps[w],
                                qf, ones, o, l5, mr, kv0, rA, g, rl, qw);
        }
        if (has_next) lwrite(cur ^ 1);
        __syncthreads();
    }

    #pragma unroll
    for (int rt = 0; rt < 2; rt++)
        #pragma unroll
        for (int n = 0; n < 4; n++)
            #pragma unroll
            for (int r = 0; r < 4; r++) {
                const int gr = qw + rt * 16 + rl + r;
                attn[(long)(b * T_SEQ + gr) * EMB + h * 64 + n * 16 + rA] =
                    (__bf16)(o[rt][n][r] / l5[rt][r]);
            }
}

// ---------------- launch ----------------
extern "C" void kernel_launch(void* const* d_in, const int* in_sizes, int n_in,
                              void* d_out, int out_size, void* d_ws, size_t ws_size,
                              hipStream_t stream) {
    const float* x      = (const float*)d_in[0];
    const float* wq     = (const float*)d_in[1];
    const float* wk     = (const float*)d_in[2];
    const float* wv     = (const float*)d_in[3];
    const float* w_proj = (const float*)d_in[4];
    const float* b_proj = (const float*)d_in[5];
    const float* w1     = (const float*)d_in[6];
    const float* b1     = (const float*)d_in[7];
    const float* w2     = (const float*)d_in[8];
    const float* b2     = (const float*)d_in[9];
    const float* g1     = (const float*)d_in[10];
    const float* be1    = (const float*)d_in[11];
    const float* g2     = (const float*)d_in[12];
    const float* be2    = (const float*)d_in[13];
    float* out = (float*)d_out;

    char* ws = (char*)d_ws;
    __bf16* WqkvT = (__bf16*)ws;  ws += 3072L * 1024 * 2;
    __bf16* WprojT = (__bf16*)ws; ws += 1024L * 1024 * 2;
    __bf16* W1T = (__bf16*)ws;    ws += 4096L * 1024 * 2;
    __bf16* W2T = (__bf16*)ws;    ws += 1024L * 4096 * 2;
    __bf16* h1  = (__bf16*)ws;    ws += 4096L * 1024 * 2;
    __bf16* qkvb = (__bf16*)ws;
    __bf16* attnb = (__bf16*)(ws + 4096L * 3072 * 2);
    __bf16* ffb = (__bf16*)ws;    ws += 4096L * 3072 * 2 + 4096L * 1024 * 2;
    float* x2 = (float*)ws;
    __bf16* Vt = (__bf16*)ws;   // overlays x2 (dead before proj-GEMM writes x2)

    const dim3 tb(32, 8);
    transpose_cvt<<<dim3(2, 32, 16), tb, 0, stream>>>(wq, WqkvT,                1024, 64, 65536L, 65536L, 0.03125f);
    transpose_cvt<<<dim3(2, 32, 16), tb, 0, stream>>>(wk, WqkvT + 1024L * 1024, 1024, 64, 65536L, 65536L, 1.0f);
    transpose_cvt<<<dim3(2, 32, 16), tb, 0, stream>>>(wv, WqkvT + 2048L * 1024, 1024, 64, 65536L, 65536L, 1.0f);
    transpose_cvt<<<dim3(32, 32, 1),  tb, 0, stream>>>(w_proj, WprojT, 1024, 1024, 0, 0, 1.0f);
    transpose_cvt<<<dim3(128, 32, 1), tb, 0, stream>>>(w1, W1T, 1024, 4096, 0, 0, 1.0f);
    transpose_cvt<<<dim3(32, 128, 1), tb, 0, stream>>>(w2, W2T, 4096, 1024, 0, 0, 1.0f);

    ln_kernel<<<4096, 256, 0, stream>>>(x, g1, be1, h1);
    gemm_nt<128, 1, 0, 0, 0><<<dim3(24, 32), 256, 0, stream>>>(h1, WqkvT, nullptr, nullptr, qkvb, 4096, 3072, 1024);
    vt_transpose<<<dim3(32, 32), 256, 0, stream>>>(qkvb, Vt);
    attn_kernel<<<dim3(16, 32), 256, 0, stream>>>(qkvb, Vt, attnb);
    gemm_nt<64, 0, 0, 1, 1><<<dim3(16, 32), 256, 0, stream>>>(attnb, WprojT, b_proj, x, x2, 4096, 1024, 1024);
    ln_kernel<<<4096, 256, 0, stream>>>(x2, g2, be2, h1);
    gemm_nt<128, 1, 1, 1, 0><<<dim3(32, 32), 256, 0, stream>>>(h1, W1T, b1, nullptr, ffb, 4096, 4096, 1024);
    gemm_nt<64, 0, 0, 1, 1><<<dim3(16, 32), 256, 0, stream>>>(ffb, W2T, b2, x2, out, 4096, 1024, 4096);
}

// Round 7
// 407.708 us; speedup vs baseline: 1.0877x; 1.0877x over previous
//
#include <hip/hip_runtime.h>
#include <hip/hip_bf16.h>

typedef __bf16 bf16x8 __attribute__((ext_vector_type(8)));
typedef __bf16 bf16x4 __attribute__((ext_vector_type(4)));
typedef float f32x4 __attribute__((ext_vector_type(4)));

#define T_SEQ 2048
#define EMB 1024
#define NH 16
#define DV 64

// async global->LDS, 16B per lane (wave-uniform LDS base + lane*16 layout required)
__device__ __forceinline__ void gload16(const __bf16* g, __bf16* l) {
    __builtin_amdgcn_global_load_lds(
        (const __attribute__((address_space(1))) unsigned int*)g,
        (__attribute__((address_space(3))) unsigned int*)l, 16, 0, 0);
}

// ---------------- transpose + fp32->bf16 convert (with scale) ----------------
__global__ void transpose_cvt(const float* __restrict__ src, __bf16* __restrict__ dst,
                              int R, int C, long src_bstride, long dst_bstride, float scale) {
    __shared__ float tile[32][33];
    const int b = blockIdx.z;
    const float* s = src + (long)b * src_bstride;
    __bf16* d = dst + (long)b * dst_bstride;
    const int c0 = blockIdx.x * 32, r0 = blockIdx.y * 32;
    #pragma unroll
    for (int i = threadIdx.y; i < 32; i += 8)
        tile[i][threadIdx.x] = s[(long)(r0 + i) * C + c0 + threadIdx.x];
    __syncthreads();
    #pragma unroll
    for (int i = threadIdx.y; i < 32; i += 8)
        d[(long)(c0 + i) * R + r0 + threadIdx.x] = (__bf16)(tile[threadIdx.x][i] * scale);
}

// ---------------- V transpose: qkv -> Vt[bh][64][2048] ----------------
__global__ void vt_transpose(const __bf16* __restrict__ qkv, __bf16* __restrict__ Vt) {
    __shared__ __bf16 tile[64][72];
    const int bh = blockIdx.y, b = bh >> 4, h = bh & 15;
    const int t0 = blockIdx.x * 64;
    const __bf16* src = qkv + (long)b * T_SEQ * 3072 + 2048 + h * 64;
    const int tt = threadIdx.x >> 3, seg = threadIdx.x & 7;
    #pragma unroll
    for (int half = 0; half < 2; half++) {
        const int t = half * 32 + tt;
        bf16x8 v = *reinterpret_cast<const bf16x8*>(src + (long)(t0 + t) * 3072 + seg * 8);
        *reinterpret_cast<bf16x8*>(&tile[t][seg * 8]) = v;
    }
    __syncthreads();
    __bf16* dst = Vt + (long)bh * 64 * T_SEQ + t0;
    #pragma unroll
    for (int half = 0; half < 2; half++) {
        const int d = half * 32 + tt;
        bf16x8 v;
        #pragma unroll
        for (int i = 0; i < 8; i++) v[i] = tile[seg * 8 + i][d];
        *reinterpret_cast<bf16x8*>(dst + (long)d * T_SEQ + seg * 8) = v;
    }
}

// ---------------- LayerNorm: fp32 in -> bf16 out ----------------
__global__ void ln_kernel(const float* __restrict__ x, const float* __restrict__ g,
                          const float* __restrict__ be, __bf16* __restrict__ out) {
    const int row = blockIdx.x;
    const float4 xv = reinterpret_cast<const float4*>(x + (long)row * EMB)[threadIdx.x];
    float s = xv.x + xv.y + xv.z + xv.w;
    float sq = xv.x * xv.x + xv.y * xv.y + xv.z * xv.z + xv.w * xv.w;
    #pragma unroll
    for (int off = 32; off; off >>= 1) { s += __shfl_down(s, off); sq += __shfl_down(sq, off); }
    __shared__ float red[8];
    const int w = threadIdx.x >> 6, lane = threadIdx.x & 63;
    if (lane == 0) { red[w] = s; red[4 + w] = sq; }
    __syncthreads();
    if (threadIdx.x == 0) {
        float st = red[0] + red[1] + red[2] + red[3];
        float sqt = red[4] + red[5] + red[6] + red[7];
        float mean = st * (1.0f / EMB);
        float var = sqt * (1.0f / EMB) - mean * mean;
        red[0] = mean; red[1] = rsqrtf(var + 1e-5f);
    }
    __syncthreads();
    const float mean = red[0], rstd = red[1];
    const float4 gv = reinterpret_cast<const float4*>(g)[threadIdx.x];
    const float4 bv = reinterpret_cast<const float4*>(be)[threadIdx.x];
    bf16x4 o;
    o[0] = (__bf16)((xv.x - mean) * rstd * gv.x + bv.x);
    o[1] = (__bf16)((xv.y - mean) * rstd * gv.y + bv.y);
    o[2] = (__bf16)((xv.z - mean) * rstd * gv.z + bv.z);
    o[3] = (__bf16)((xv.w - mean) * rstd * gv.w + bv.w);
    *reinterpret_cast<bf16x4*>(out + (long)row * EMB + threadIdx.x * 4) = o;
}

// ---------------- bf16 GEMM (NT), m97 structure + T2 swizzle ----------------
// LDS tile [rows][64] linear dest for global_load_lds; SOURCE chunk pre-swizzled
// (chunk ^ (row&7)) and ds_read XOR-swizzled (elem ^ (row&7)*8): rule #21.
template <int BN, int OUT_BF16, int RELU, int HAS_BIAS, int HAS_RES>
__global__ __launch_bounds__(256)
void gemm_nt(const __bf16* __restrict__ A, const __bf16* __restrict__ BT,
             const float* __restrict__ bias, const float* __restrict__ res,
             void* __restrict__ outp, int M, int N, int K) {
    constexpr int NFN = BN / 32;                 // 16-wide n-frags per wave
    __shared__ __align__(16) __bf16 As[128 * 64];
    __shared__ __align__(16) __bf16 Bs[BN * 64];
    const int t = threadIdx.x;
    const int w = t >> 6, lane = t & 63;
    const int wm = (w >> 1) * 64, wn = (w & 1) * (BN / 2);
    const int m0 = blockIdx.y * 128, n0 = blockIdx.x * BN;
    const int rA = lane & 15, kA = (lane >> 4) * 8;
    const int swzr = (rA & 7) * 8;               // read-side XOR (elements)
    const int srow = t >> 3;                     // 0..31
    const int chunk = t & 7;
    const int schunk = chunk ^ (srow & 7);       // pre-swizzled source chunk

    const __bf16* Ab = A + (long)(m0 + srow) * K + schunk * 8;
    const __bf16* Bb = BT + (long)(n0 + srow) * K + schunk * 8;
    __bf16* Asw = As + srow * 64 + chunk * 8;    // linear: base + lane*16B
    __bf16* Bsw = Bs + srow * 64 + chunk * 8;

    f32x4 acc[4][NFN] = {};
    for (int k0 = 0; k0 < K; k0 += 64) {
        #pragma unroll
        for (int i = 0; i < 4; i++)
            gload16(Ab + (long)(32 * i) * K + k0, Asw + 32 * i * 64);
        #pragma unroll
        for (int i = 0; i < BN / 32; i++)
            gload16(Bb + (long)(32 * i) * K + k0, Bsw + 32 * i * 64);
        __syncthreads();   // compiler drains vmcnt before barrier
        #pragma unroll
        for (int kk = 0; kk < 2; kk++) {
            bf16x8 af[4], bfr[NFN];
            #pragma unroll
            for (int m = 0; m < 4; m++)
                af[m] = *reinterpret_cast<const bf16x8*>(
                    As + (wm + m * 16 + rA) * 64 + ((kk * 32 + kA) ^ swzr));
            #pragma unroll
            for (int n = 0; n < NFN; n++)
                bfr[n] = *reinterpret_cast<const bf16x8*>(
                    Bs + (wn + n * 16 + rA) * 64 + ((kk * 32 + kA) ^ swzr));
            #pragma unroll
            for (int m = 0; m < 4; m++)
                #pragma unroll
                for (int n = 0; n < NFN; n++)
                    acc[m][n] = __builtin_amdgcn_mfma_f32_16x16x32_bf16(af[m], bfr[n], acc[m][n], 0, 0, 0);
        }
        __syncthreads();
    }
    const int rl = (lane >> 4) * 4, cl = lane & 15;
    #pragma unroll
    for (int m = 0; m < 4; m++) {
        #pragma unroll
        for (int n = 0; n < NFN; n++) {
            const int gc = n0 + wn + n * 16 + cl;
            float bval = 0.0f;
            if (HAS_BIAS) bval = bias[gc];
            #pragma unroll
            for (int r = 0; r < 4; r++) {
                const int gr = m0 + wm + m * 16 + rl + r;
                float v = acc[m][n][r] + bval;
                if (HAS_RES) v += res[(long)gr * N + gc];
                if (RELU) v = fmaxf(v, 0.0f);
                if (OUT_BF16) ((__bf16*)outp)[(long)gr * N + gc] = (__bf16)v;
                else          ((float*)outp)[(long)gr * N + gc] = v;
            }
        }
    }
}

// ---------------- causal flash attention: LDS-staged, double-buffered ----------------
template <int MASKED>
__device__ __forceinline__ void attn_compute(
    const char* __restrict__ Kl, const char* __restrict__ Vl,
    __bf16 (*__restrict__ PsW)[72],
    const bf16x8 (&qf)[2][2], const bf16x8& ones,
    f32x4 (&o)[2][4], f32x4 (&l5)[2], float (&mr)[2][4],
    int kv0, int rA, int g, int rl, int qw)
{
    const int swz = (rA & 7) << 4;
    bf16x8 kf[4][2];
    #pragma unroll
    for (int c = 0; c < 4; c++)
        #pragma unroll
        for (int kc = 0; kc < 2; kc++)
            kf[c][kc] = *reinterpret_cast<const bf16x8*>(
                Kl + (c * 16 + rA) * 128 + ((kc * 64 + g * 16) ^ swz));
    f32x4 sa[2][4];
    __builtin_amdgcn_s_setprio(1);
    #pragma unroll
    for (int rt = 0; rt < 2; rt++)
        #pragma unroll
        for (int c = 0; c < 4; c++) {
            f32x4 acc = {};
            acc = __builtin_amdgcn_mfma_f32_16x16x32_bf16(qf[rt][0], kf[c][0], acc, 0, 0, 0);
            acc = __builtin_amdgcn_mfma_f32_16x16x32_bf16(qf[rt][1], kf[c][1], acc, 0, 0, 0);
            sa[rt][c] = acc;
        }
    __builtin_amdgcn_s_setprio(0);
    #pragma unroll
    for (int rt = 0; rt < 2; rt++) {
        #pragma unroll
        for (int r = 0; r < 4; r++) {
            float s0 = sa[rt][0][r], s1 = sa[rt][1][r], s2 = sa[rt][2][r], s3 = sa[rt][3][r];
            if (MASKED) {
                const int gr = qw + rt * 16 + rl + r;
                if (kv0 + rA > gr)      s0 = -__builtin_inff();
                if (kv0 + 16 + rA > gr) s1 = -__builtin_inff();
                if (kv0 + 32 + rA > gr) s2 = -__builtin_inff();
                if (kv0 + 48 + rA > gr) s3 = -__builtin_inff();
            }
            float tm = fmaxf(fmaxf(s0, s1), fmaxf(s2, s3));
            #pragma unroll
            for (int msk = 1; msk < 16; msk <<= 1) tm = fmaxf(tm, __shfl_xor(tm, msk));
            const float mo = mr[rt][r];
            const float mn = fmaxf(mo, tm);
            mr[rt][r] = mn;
            const float sc = __expf(mo - mn);
            const float p0 = __expf(s0 - mn);
            const float p1 = __expf(s1 - mn);
            const float p2 = __expf(s2 - mn);
            const float p3 = __expf(s3 - mn);
            #pragma unroll
            for (int n = 0; n < 4; n++) o[rt][n][r] *= sc;
            l5[rt][r] *= sc;
            const int prow = rt * 16 + rl + r;
            PsW[prow][rA]      = (__bf16)p0;
            PsW[prow][16 + rA] = (__bf16)p1;
            PsW[prow][32 + rA] = (__bf16)p2;
            PsW[prow][48 + rA] = (__bf16)p3;
        }
    }
    asm volatile("s_waitcnt lgkmcnt(0)" ::: "memory");

    bf16x8 ap[2][2];
    #pragma unroll
    for (int rt = 0; rt < 2; rt++)
        #pragma unroll
        for (int ks = 0; ks < 2; ks++)
            ap[rt][ks] = *reinterpret_cast<const bf16x8*>(&PsW[rt * 16 + rA][ks * 32 + g * 8]);
    __builtin_amdgcn_s_setprio(1);
    #pragma unroll
    for (int ks = 0; ks < 2; ks++) {
        #pragma unroll
        for (int rt = 0; rt < 2; rt++)
            l5[rt] = __builtin_amdgcn_mfma_f32_16x16x32_bf16(ap[rt][ks], ones, l5[rt], 0, 0, 0);
        #pragma unroll
        for (int n = 0; n < 4; n++) {
            bf16x8 bv = *reinterpret_cast<const bf16x8*>(
                Vl + (n * 16 + rA) * 128 + ((ks * 64 + g * 16) ^ swz));
            #pragma unroll
            for (int rt = 0; rt < 2; rt++)
                o[rt][n] = __builtin_amdgcn_mfma_f32_16x16x32_bf16(ap[rt][ks], bv, o[rt][n], 0, 0, 0);
        }
    }
    __builtin_amdgcn_s_setprio(0);
}

// grid: 512 blocks (flattened). XCD-aware remap: all 16 q-tiles of a head on
// one XCD (4 heads/XCD; K+V of 4 heads = 2MB fits 4MB L2; all blocks co-resident).
__global__ __launch_bounds__(256)
void attn_kernel(const __bf16* __restrict__ qkv, const __bf16* __restrict__ Vt,
                 __bf16* __restrict__ attn) {
    __shared__ __bf16 Ks[2][64 * 64];
    __shared__ __bf16 Vs[2][64 * 64];
    __shared__ __bf16 Ps[4][32][72];

    const int bid = (int)blockIdx.x;
    const int wgid = (bid & 7) * 64 + (bid >> 3);   // m157 swizzle, 512 % 8 == 0
    const int bh = wgid >> 4, b = bh >> 4, h = bh & 15;
    const int qtile = 15 - (wgid & 15);             // heavy tiles first within XCD
    const int q0 = qtile * 128;
    const int w = threadIdx.x >> 6, lane = threadIdx.x & 63;
    const int qw = q0 + w * 32;
    const int rA = lane & 15, g = lane >> 4, rl = g * 4;
    const int srow8 = lane >> 3;
    const int scol = (lane & 7) * 16;
    const int wcol = scol ^ (srow8 << 4);

    const char* qb = (const char*)(qkv + (long)b * T_SEQ * 3072 + h * 64);
    const char* kb = qb + 2048;
    const char* vtb = (const char*)(Vt + (long)bh * 64 * T_SEQ);

    bf16x8 qf[2][2];
    #pragma unroll
    for (int rt = 0; rt < 2; rt++)
        #pragma unroll
        for (int kc = 0; kc < 2; kc++)
            qf[rt][kc] = *reinterpret_cast<const bf16x8*>(
                qb + (long)(qw + rt * 16 + rA) * 6144 + kc * 64 + g * 16);

    bf16x8 ones;
    #pragma unroll
    for (int i = 0; i < 8; i++) ones[i] = (__bf16)1.0f;

    f32x4 o[2][4] = {};
    f32x4 l5[2] = {};
    float mr[2][4];
    #pragma unroll
    for (int rt = 0; rt < 2; rt++)
        #pragma unroll
        for (int r = 0; r < 4; r++) mr[rt][r] = -__builtin_inff();

    const int nsteps = q0 / 64 + 2;
    const int t_avail = qw + 32;
    const int isK = (w < 2);
    const int r0 = (w & 1) * 32 + srow8;

    bf16x8 stg[4];
    auto issue = [&](int kv0) {
        if (isK) {
            #pragma unroll
            for (int i = 0; i < 4; i++)
                stg[i] = *reinterpret_cast<const bf16x8*>(kb + (long)(kv0 + r0 + i * 8) * 6144 + scol);
        } else {
            #pragma unroll
            for (int i = 0; i < 4; i++)
                stg[i] = *reinterpret_cast<const bf16x8*>(vtb + (long)(r0 + i * 8) * 4096 + kv0 * 2 + scol);
        }
    };
    auto lwrite = [&](int buf) {
        char* base = isK ? (char*)Ks[buf] : (char*)Vs[buf];
        #pragma unroll
        for (int i = 0; i < 4; i++)
            *reinterpret_cast<bf16x8*>(base + (r0 + i * 8) * 128 + wcol) = stg[i];
    };

    issue(0);
    lwrite(0);
    __syncthreads();

    for (int t = 0; t < nsteps; ++t) {
        const int kv0 = t * 64, cur = t & 1;
        const bool has_next = (t + 1 < nsteps);
        if (has_next) issue(kv0 + 64);
        if (kv0 < t_avail) {
            if (kv0 + 64 <= qw)
                attn_compute<0>((const char*)Ks[cur], (const char*)Vs[cur], Ps[w],
                                qf, ones, o, l5, mr, kv0, rA, g, rl, qw);
            else
                attn_compute<1>((const char*)Ks[cur], (const char*)Vs[cur], Ps[w],
                                qf, ones, o, l5, mr, kv0, rA, g, rl, qw);
        }
        if (has_next) lwrite(cur ^ 1);
        __syncthreads();
    }

    #pragma unroll
    for (int rt = 0; rt < 2; rt++)
        #pragma unroll
        for (int n = 0; n < 4; n++)
            #pragma unroll
            for (int r = 0; r < 4; r++) {
                const int gr = qw + rt * 16 + rl + r;
                attn[(long)(b * T_SEQ + gr) * EMB + h * 64 + n * 16 + rA] =
                    (__bf16)(o[rt][n][r] / l5[rt][r]);
            }
}

// ---------------- launch ----------------
extern "C" void kernel_launch(void* const* d_in, const int* in_sizes, int n_in,
                              void* d_out, int out_size, void* d_ws, size_t ws_size,
                              hipStream_t stream) {
    const float* x      = (const float*)d_in[0];
    const float* wq     = (const float*)d_in[1];
    const float* wk     = (const float*)d_in[2];
    const float* wv     = (const float*)d_in[3];
    const float* w_proj = (const float*)d_in[4];
    const float* b_proj = (const float*)d_in[5];
    const float* w1     = (const float*)d_in[6];
    const float* b1     = (const float*)d_in[7];
    const float* w2     = (const float*)d_in[8];
    const float* b2     = (const float*)d_in[9];
    const float* g1     = (const float*)d_in[10];
    const float* be1    = (const float*)d_in[11];
    const float* g2     = (const float*)d_in[12];
    const float* be2    = (const float*)d_in[13];
    float* out = (float*)d_out;

    char* ws = (char*)d_ws;
    __bf16* WqkvT = (__bf16*)ws;  ws += 3072L * 1024 * 2;
    __bf16* WprojT = (__bf16*)ws; ws += 1024L * 1024 * 2;
    __bf16* W1T = (__bf16*)ws;    ws += 4096L * 1024 * 2;
    __bf16* W2T = (__bf16*)ws;    ws += 1024L * 4096 * 2;
    __bf16* h1  = (__bf16*)ws;    ws += 4096L * 1024 * 2;
    __bf16* qkvb = (__bf16*)ws;
    __bf16* attnb = (__bf16*)(ws + 4096L * 3072 * 2);
    __bf16* ffb = (__bf16*)ws;    ws += 4096L * 3072 * 2 + 4096L * 1024 * 2;
    float* x2 = (float*)ws;
    __bf16* Vt = (__bf16*)ws;   // overlays x2 (dead before proj-GEMM writes x2)

    const dim3 tb(32, 8);
    transpose_cvt<<<dim3(2, 32, 16), tb, 0, stream>>>(wq, WqkvT,                1024, 64, 65536L, 65536L, 0.03125f);
    transpose_cvt<<<dim3(2, 32, 16), tb, 0, stream>>>(wk, WqkvT + 1024L * 1024, 1024, 64, 65536L, 65536L, 1.0f);
    transpose_cvt<<<dim3(2, 32, 16), tb, 0, stream>>>(wv, WqkvT + 2048L * 1024, 1024, 64, 65536L, 65536L, 1.0f);
    transpose_cvt<<<dim3(32, 32, 1),  tb, 0, stream>>>(w_proj, WprojT, 1024, 1024, 0, 0, 1.0f);
    transpose_cvt<<<dim3(128, 32, 1), tb, 0, stream>>>(w1, W1T, 1024, 4096, 0, 0, 1.0f);
    transpose_cvt<<<dim3(32, 128, 1), tb, 0, stream>>>(w2, W2T, 4096, 1024, 0, 0, 1.0f);

    ln_kernel<<<4096, 256, 0, stream>>>(x, g1, be1, h1);
    gemm_nt<128, 1, 0, 0, 0><<<dim3(24, 32), 256, 0, stream>>>(h1, WqkvT, nullptr, nullptr, qkvb, 4096, 3072, 1024);
    vt_transpose<<<dim3(32, 32), 256, 0, stream>>>(qkvb, Vt);
    attn_kernel<<<512, 256, 0, stream>>>(qkvb, Vt, attnb);
    gemm_nt<64, 0, 0, 1, 1><<<dim3(16, 32), 256, 0, stream>>>(attnb, WprojT, b_proj, x, x2, 4096, 1024, 1024);
    ln_kernel<<<4096, 256, 0, stream>>>(x2, g2, be2, h1);
    gemm_nt<128, 1, 1, 1, 0><<<dim3(32, 32), 256, 0, stream>>>(h1, W1T, b1, nullptr, ffb, 4096, 4096, 1024);
    gemm_nt<64, 0, 0, 1, 1><<<dim3(16, 32), 256, 0, stream>>>(ffb, W2T, b2, x2, out, 4096, 1024, 4096);
}

// Round 8
// 399.730 us; speedup vs baseline: 1.1094x; 1.0200x over previous
//
#include <hip/hip_runtime.h>
#include <hip/hip_bf16.h>

typedef __bf16 bf16x8 __attribute__((ext_vector_type(8)));
typedef __bf16 bf16x4 __attribute__((ext_vector_type(4)));
typedef float f32x4 __attribute__((ext_vector_type(4)));

#define T_SEQ 2048
#define EMB 1024
#define NH 16
#define DV 64

// async global->LDS, 16B per lane (wave-uniform LDS base + lane*16 layout required)
__device__ __forceinline__ void gload16(const __bf16* g, __bf16* l) {
    __builtin_amdgcn_global_load_lds(
        (const __attribute__((address_space(1))) unsigned int*)g,
        (__attribute__((address_space(3))) unsigned int*)l, 16, 0, 0);
}

// ---------------- transpose + fp32->bf16 convert (with scale) ----------------
__global__ void transpose_cvt(const float* __restrict__ src, __bf16* __restrict__ dst,
                              int R, int C, long src_bstride, long dst_bstride, float scale) {
    __shared__ float tile[32][33];
    const int b = blockIdx.z;
    const float* s = src + (long)b * src_bstride;
    __bf16* d = dst + (long)b * dst_bstride;
    const int c0 = blockIdx.x * 32, r0 = blockIdx.y * 32;
    #pragma unroll
    for (int i = threadIdx.y; i < 32; i += 8)
        tile[i][threadIdx.x] = s[(long)(r0 + i) * C + c0 + threadIdx.x];
    __syncthreads();
    #pragma unroll
    for (int i = threadIdx.y; i < 32; i += 8)
        d[(long)(c0 + i) * R + r0 + threadIdx.x] = (__bf16)(tile[threadIdx.x][i] * scale);
}

// ---------------- V transpose: qkv -> Vt[bh][64][2048] ----------------
__global__ void vt_transpose(const __bf16* __restrict__ qkv, __bf16* __restrict__ Vt) {
    __shared__ __bf16 tile[64][72];
    const int bh = blockIdx.y, b = bh >> 4, h = bh & 15;
    const int t0 = blockIdx.x * 64;
    const __bf16* src = qkv + (long)b * T_SEQ * 3072 + 2048 + h * 64;
    const int tt = threadIdx.x >> 3, seg = threadIdx.x & 7;
    #pragma unroll
    for (int half = 0; half < 2; half++) {
        const int t = half * 32 + tt;
        bf16x8 v = *reinterpret_cast<const bf16x8*>(src + (long)(t0 + t) * 3072 + seg * 8);
        *reinterpret_cast<bf16x8*>(&tile[t][seg * 8]) = v;
    }
    __syncthreads();
    __bf16* dst = Vt + (long)bh * 64 * T_SEQ + t0;
    #pragma unroll
    for (int half = 0; half < 2; half++) {
        const int d = half * 32 + tt;
        bf16x8 v;
        #pragma unroll
        for (int i = 0; i < 8; i++) v[i] = tile[seg * 8 + i][d];
        *reinterpret_cast<bf16x8*>(dst + (long)d * T_SEQ + seg * 8) = v;
    }
}

// ---------------- LayerNorm: fp32 in -> bf16 out ----------------
__global__ void ln_kernel(const float* __restrict__ x, const float* __restrict__ g,
                          const float* __restrict__ be, __bf16* __restrict__ out) {
    const int row = blockIdx.x;
    const float4 xv = reinterpret_cast<const float4*>(x + (long)row * EMB)[threadIdx.x];
    float s = xv.x + xv.y + xv.z + xv.w;
    float sq = xv.x * xv.x + xv.y * xv.y + xv.z * xv.z + xv.w * xv.w;
    #pragma unroll
    for (int off = 32; off; off >>= 1) { s += __shfl_down(s, off); sq += __shfl_down(sq, off); }
    __shared__ float red[8];
    const int w = threadIdx.x >> 6, lane = threadIdx.x & 63;
    if (lane == 0) { red[w] = s; red[4 + w] = sq; }
    __syncthreads();
    if (threadIdx.x == 0) {
        float st = red[0] + red[1] + red[2] + red[3];
        float sqt = red[4] + red[5] + red[6] + red[7];
        float mean = st * (1.0f / EMB);
        float var = sqt * (1.0f / EMB) - mean * mean;
        red[0] = mean; red[1] = rsqrtf(var + 1e-5f);
    }
    __syncthreads();
    const float mean = red[0], rstd = red[1];
    const float4 gv = reinterpret_cast<const float4*>(g)[threadIdx.x];
    const float4 bv = reinterpret_cast<const float4*>(be)[threadIdx.x];
    bf16x4 o;
    o[0] = (__bf16)((xv.x - mean) * rstd * gv.x + bv.x);
    o[1] = (__bf16)((xv.y - mean) * rstd * gv.y + bv.y);
    o[2] = (__bf16)((xv.z - mean) * rstd * gv.z + bv.z);
    o[3] = (__bf16)((xv.w - mean) * rstd * gv.w + bv.w);
    *reinterpret_cast<bf16x4*>(out + (long)row * EMB + threadIdx.x * 4) = o;
}

// ---------------- bf16 GEMM (NT), m97 structure + T2 swizzle ----------------
template <int BN, int OUT_BF16, int RELU, int HAS_BIAS, int HAS_RES>
__global__ __launch_bounds__(256)
void gemm_nt(const __bf16* __restrict__ A, const __bf16* __restrict__ BT,
             const float* __restrict__ bias, const float* __restrict__ res,
             void* __restrict__ outp, int M, int N, int K) {
    constexpr int NFN = BN / 32;                 // 16-wide n-frags per wave
    __shared__ __align__(16) __bf16 As[128 * 64];
    __shared__ __align__(16) __bf16 Bs[BN * 64];
    const int t = threadIdx.x;
    const int w = t >> 6, lane = t & 63;
    const int wm = (w >> 1) * 64, wn = (w & 1) * (BN / 2);
    const int m0 = blockIdx.y * 128, n0 = blockIdx.x * BN;
    const int rA = lane & 15, kA = (lane >> 4) * 8;
    const int swzr = (rA & 7) * 8;               // read-side XOR (elements)
    const int srow = t >> 3;                     // 0..31
    const int chunk = t & 7;
    const int schunk = chunk ^ (srow & 7);       // pre-swizzled source chunk

    const __bf16* Ab = A + (long)(m0 + srow) * K + schunk * 8;
    const __bf16* Bb = BT + (long)(n0 + srow) * K + schunk * 8;
    __bf16* Asw = As + srow * 64 + chunk * 8;    // linear: base + lane*16B
    __bf16* Bsw = Bs + srow * 64 + chunk * 8;

    f32x4 acc[4][NFN] = {};
    for (int k0 = 0; k0 < K; k0 += 64) {
        #pragma unroll
        for (int i = 0; i < 4; i++)
            gload16(Ab + (long)(32 * i) * K + k0, Asw + 32 * i * 64);
        #pragma unroll
        for (int i = 0; i < BN / 32; i++)
            gload16(Bb + (long)(32 * i) * K + k0, Bsw + 32 * i * 64);
        __syncthreads();   // compiler drains vmcnt before barrier
        #pragma unroll
        for (int kk = 0; kk < 2; kk++) {
            bf16x8 af[4], bfr[NFN];
            #pragma unroll
            for (int m = 0; m < 4; m++)
                af[m] = *reinterpret_cast<const bf16x8*>(
                    As + (wm + m * 16 + rA) * 64 + ((kk * 32 + kA) ^ swzr));
            #pragma unroll
            for (int n = 0; n < NFN; n++)
                bfr[n] = *reinterpret_cast<const bf16x8*>(
                    Bs + (wn + n * 16 + rA) * 64 + ((kk * 32 + kA) ^ swzr));
            #pragma unroll
            for (int m = 0; m < 4; m++)
                #pragma unroll
                for (int n = 0; n < NFN; n++)
                    acc[m][n] = __builtin_amdgcn_mfma_f32_16x16x32_bf16(af[m], bfr[n], acc[m][n], 0, 0, 0);
        }
        __syncthreads();
    }
    const int rl = (lane >> 4) * 4, cl = lane & 15;
    #pragma unroll
    for (int m = 0; m < 4; m++) {
        #pragma unroll
        for (int n = 0; n < NFN; n++) {
            const int gc = n0 + wn + n * 16 + cl;
            float bval = 0.0f;
            if (HAS_BIAS) bval = bias[gc];
            #pragma unroll
            for (int r = 0; r < 4; r++) {
                const int gr = m0 + wm + m * 16 + rl + r;
                float v = acc[m][n][r] + bval;
                if (HAS_RES) v += res[(long)gr * N + gc];
                if (RELU) v = fmaxf(v, 0.0f);
                if (OUT_BF16) ((__bf16*)outp)[(long)gr * N + gc] = (__bf16)v;
                else          ((float*)outp)[(long)gr * N + gc] = v;
            }
        }
    }
}

// ---------------- causal flash attention: LDS-staged, double-buffered ----------------
template <int MASKED>
__device__ __forceinline__ void attn_compute(
    const char* __restrict__ Kl, const char* __restrict__ Vl,
    __bf16 (*__restrict__ PsW)[72],
    const bf16x8 (&qf)[2][2], const bf16x8& ones,
    f32x4 (&o)[2][4], f32x4 (&l5)[2], float (&mr)[2][4],
    int kv0, int rA, int g, int rl, int qw)
{
    const int swz = (rA & 7) << 4;
    bf16x8 kf[4][2];
    #pragma unroll
    for (int c = 0; c < 4; c++)
        #pragma unroll
        for (int kc = 0; kc < 2; kc++)
            kf[c][kc] = *reinterpret_cast<const bf16x8*>(
                Kl + (c * 16 + rA) * 128 + ((kc * 64 + g * 16) ^ swz));
    f32x4 sa[2][4];
    __builtin_amdgcn_s_setprio(1);
    #pragma unroll
    for (int rt = 0; rt < 2; rt++)
        #pragma unroll
        for (int c = 0; c < 4; c++) {
            f32x4 acc = {};
            acc = __builtin_amdgcn_mfma_f32_16x16x32_bf16(qf[rt][0], kf[c][0], acc, 0, 0, 0);
            acc = __builtin_amdgcn_mfma_f32_16x16x32_bf16(qf[rt][1], kf[c][1], acc, 0, 0, 0);
            sa[rt][c] = acc;
        }
    __builtin_amdgcn_s_setprio(0);
    #pragma unroll
    for (int rt = 0; rt < 2; rt++) {
        #pragma unroll
        for (int r = 0; r < 4; r++) {
            float s0 = sa[rt][0][r], s1 = sa[rt][1][r], s2 = sa[rt][2][r], s3 = sa[rt][3][r];
            if (MASKED) {
                const int gr = qw + rt * 16 + rl + r;
                if (kv0 + rA > gr)      s0 = -__builtin_inff();
                if (kv0 + 16 + rA > gr) s1 = -__builtin_inff();
                if (kv0 + 32 + rA > gr) s2 = -__builtin_inff();
                if (kv0 + 48 + rA > gr) s3 = -__builtin_inff();
            }
            float tm = fmaxf(fmaxf(s0, s1), fmaxf(s2, s3));
            #pragma unroll
            for (int msk = 1; msk < 16; msk <<= 1) tm = fmaxf(tm, __shfl_xor(tm, msk));
            const float mo = mr[rt][r];
            // T13 defer-max: skip O-rescale while max growth <= 8 (P bounded by e^8)
            float mu = mo;
            if (__any(tm > mo + 8.0f)) {
                const float mn = fmaxf(mo, tm);
                mr[rt][r] = mn;
                const float sc = __expf(mo - mn);
                #pragma unroll
                for (int n = 0; n < 4; n++) o[rt][n][r] *= sc;
                l5[rt][r] *= sc;
                mu = mn;
            }
            const float p0 = __expf(s0 - mu);
            const float p1 = __expf(s1 - mu);
            const float p2 = __expf(s2 - mu);
            const float p3 = __expf(s3 - mu);
            const int prow = rt * 16 + rl + r;
            PsW[prow][rA]      = (__bf16)p0;
            PsW[prow][16 + rA] = (__bf16)p1;
            PsW[prow][32 + rA] = (__bf16)p2;
            PsW[prow][48 + rA] = (__bf16)p3;
        }
    }
    asm volatile("s_waitcnt lgkmcnt(0)" ::: "memory");

    bf16x8 ap[2][2];
    #pragma unroll
    for (int rt = 0; rt < 2; rt++)
        #pragma unroll
        for (int ks = 0; ks < 2; ks++)
            ap[rt][ks] = *reinterpret_cast<const bf16x8*>(&PsW[rt * 16 + rA][ks * 32 + g * 8]);
    __builtin_amdgcn_s_setprio(1);
    #pragma unroll
    for (int ks = 0; ks < 2; ks++) {
        #pragma unroll
        for (int rt = 0; rt < 2; rt++)
            l5[rt] = __builtin_amdgcn_mfma_f32_16x16x32_bf16(ap[rt][ks], ones, l5[rt], 0, 0, 0);
        #pragma unroll
        for (int n = 0; n < 4; n++) {
            bf16x8 bv = *reinterpret_cast<const bf16x8*>(
                Vl + (n * 16 + rA) * 128 + ((ks * 64 + g * 16) ^ swz));
            #pragma unroll
            for (int rt = 0; rt < 2; rt++)
                o[rt][n] = __builtin_amdgcn_mfma_f32_16x16x32_bf16(ap[rt][ks], bv, o[rt][n], 0, 0, 0);
        }
    }
    __builtin_amdgcn_s_setprio(0);
}

// grid: 512 blocks. XCD-confined heads (4/XCD) + complementary heavy/light
// pairing: intra-XCD slot0 (s<32) tiles descending, slot1 ascending, so each
// CU's two resident blocks sum to a constant 36 KV-steps (LPT balance).
__global__ __launch_bounds__(256)
void attn_kernel(const __bf16* __restrict__ qkv, const __bf16* __restrict__ Vt,
                 __bf16* __restrict__ attn) {
    __shared__ __bf16 Ks[2][64 * 64];
    __shared__ __bf16 Vs[2][64 * 64];
    __shared__ __bf16 Ps[4][32][72];

    const int bid = (int)blockIdx.x;
    const int xcd = bid & 7, s = bid >> 3;          // dispatch: round-robin XCDs
    const int slot = s >> 5, c = s & 31;
    const int bh = xcd * 4 + slot * 2 + (c >> 4);
    const int t16 = c & 15;
    const int qtile = slot ? t16 : 15 - t16;        // desc then asc: CU pair sums const
    const int b = bh >> 4, h = bh & 15;
    const int q0 = qtile * 128;
    const int w = threadIdx.x >> 6, lane = threadIdx.x & 63;
    const int qw = q0 + w * 32;
    const int rA = lane & 15, g = lane >> 4, rl = g * 4;
    const int srow8 = lane >> 3;
    const int scol = (lane & 7) * 16;
    const int wcol = scol ^ (srow8 << 4);

    const char* qb = (const char*)(qkv + (long)b * T_SEQ * 3072 + h * 64);
    const char* kb = qb + 2048;
    const char* vtb = (const char*)(Vt + (long)bh * 64 * T_SEQ);

    bf16x8 qf[2][2];
    #pragma unroll
    for (int rt = 0; rt < 2; rt++)
        #pragma unroll
        for (int kc = 0; kc < 2; kc++)
            qf[rt][kc] = *reinterpret_cast<const bf16x8*>(
                qb + (long)(qw + rt * 16 + rA) * 6144 + kc * 64 + g * 16);

    bf16x8 ones;
    #pragma unroll
    for (int i = 0; i < 8; i++) ones[i] = (__bf16)1.0f;

    f32x4 o[2][4] = {};
    f32x4 l5[2] = {};
    float mr[2][4];
    #pragma unroll
    for (int rt = 0; rt < 2; rt++)
        #pragma unroll
        for (int r = 0; r < 4; r++) mr[rt][r] = -__builtin_inff();

    const int nsteps = q0 / 64 + 2;
    const int t_avail = qw + 32;
    const int isK = (w < 2);
    const int r0 = (w & 1) * 32 + srow8;

    bf16x8 stg[4];
    auto issue = [&](int kv0) {
        if (isK) {
            #pragma unroll
            for (int i = 0; i < 4; i++)
                stg[i] = *reinterpret_cast<const bf16x8*>(kb + (long)(kv0 + r0 + i * 8) * 6144 + scol);
        } else {
            #pragma unroll
            for (int i = 0; i < 4; i++)
                stg[i] = *reinterpret_cast<const bf16x8*>(vtb + (long)(r0 + i * 8) * 4096 + kv0 * 2 + scol);
        }
    };
    auto lwrite = [&](int buf) {
        char* base = isK ? (char*)Ks[buf] : (char*)Vs[buf];
        #pragma unroll
        for (int i = 0; i < 4; i++)
            *reinterpret_cast<bf16x8*>(base + (r0 + i * 8) * 128 + wcol) = stg[i];
    };

    issue(0);
    lwrite(0);
    __syncthreads();

    for (int t = 0; t < nsteps; ++t) {
        const int kv0 = t * 64, cur = t & 1;
        const bool has_next = (t + 1 < nsteps);
        if (has_next) issue(kv0 + 64);
        if (kv0 < t_avail) {
            if (kv0 + 64 <= qw)
                attn_compute<0>((const char*)Ks[cur], (const char*)Vs[cur], Ps[w],
                                qf, ones, o, l5, mr, kv0, rA, g, rl, qw);
            else
                attn_compute<1>((const char*)Ks[cur], (const char*)Vs[cur], Ps[w],
                                qf, ones, o, l5, mr, kv0, rA, g, rl, qw);
        }
        if (has_next) lwrite(cur ^ 1);
        __syncthreads();
    }

    #pragma unroll
    for (int rt = 0; rt < 2; rt++)
        #pragma unroll
        for (int n = 0; n < 4; n++)
            #pragma unroll
            for (int r = 0; r < 4; r++) {
                const int gr = qw + rt * 16 + rl + r;
                attn[(long)(b * T_SEQ + gr) * EMB + h * 64 + n * 16 + rA] =
                    (__bf16)(o[rt][n][r] / l5[rt][r]);
            }
}

// ---------------- launch ----------------
extern "C" void kernel_launch(void* const* d_in, const int* in_sizes, int n_in,
                              void* d_out, int out_size, void* d_ws, size_t ws_size,
                              hipStream_t stream) {
    const float* x      = (const float*)d_in[0];
    const float* wq     = (const float*)d_in[1];
    const float* wk     = (const float*)d_in[2];
    const float* wv     = (const float*)d_in[3];
    const float* w_proj = (const float*)d_in[4];
    const float* b_proj = (const float*)d_in[5];
    const float* w1     = (const float*)d_in[6];
    const float* b1     = (const float*)d_in[7];
    const float* w2     = (const float*)d_in[8];
    const float* b2     = (const float*)d_in[9];
    const float* g1     = (const float*)d_in[10];
    const float* be1    = (const float*)d_in[11];
    const float* g2     = (const float*)d_in[12];
    const float* be2    = (const float*)d_in[13];
    float* out = (float*)d_out;

    char* ws = (char*)d_ws;
    __bf16* WqkvT = (__bf16*)ws;  ws += 3072L * 1024 * 2;
    __bf16* WprojT = (__bf16*)ws; ws += 1024L * 1024 * 2;
    __bf16* W1T = (__bf16*)ws;    ws += 4096L * 1024 * 2;
    __bf16* W2T = (__bf16*)ws;    ws += 1024L * 4096 * 2;
    __bf16* h1  = (__bf16*)ws;    ws += 4096L * 1024 * 2;
    __bf16* qkvb = (__bf16*)ws;
    __bf16* attnb = (__bf16*)(ws + 4096L * 3072 * 2);
    __bf16* ffb = (__bf16*)ws;    ws += 4096L * 3072 * 2 + 4096L * 1024 * 2;
    float* x2 = (float*)ws;
    __bf16* Vt = (__bf16*)ws;   // overlays x2 (dead before proj-GEMM writes x2)

    const dim3 tb(32, 8);
    transpose_cvt<<<dim3(2, 32, 16), tb, 0, stream>>>(wq, WqkvT,                1024, 64, 65536L, 65536L, 0.03125f);
    transpose_cvt<<<dim3(2, 32, 16), tb, 0, stream>>>(wk, WqkvT + 1024L * 1024, 1024, 64, 65536L, 65536L, 1.0f);
    transpose_cvt<<<dim3(2, 32, 16), tb, 0, stream>>>(wv, WqkvT + 2048L * 1024, 1024, 64, 65536L, 65536L, 1.0f);
    transpose_cvt<<<dim3(32, 32, 1),  tb, 0, stream>>>(w_proj, WprojT, 1024, 1024, 0, 0, 1.0f);
    transpose_cvt<<<dim3(128, 32, 1), tb, 0, stream>>>(w1, W1T, 1024, 4096, 0, 0, 1.0f);
    transpose_cvt<<<dim3(32, 128, 1), tb, 0, stream>>>(w2, W2T, 4096, 1024, 0, 0, 1.0f);

    ln_kernel<<<4096, 256, 0, stream>>>(x, g1, be1, h1);
    gemm_nt<128, 1, 0, 0, 0><<<dim3(24, 32), 256, 0, stream>>>(h1, WqkvT, nullptr, nullptr, qkvb, 4096, 3072, 1024);
    vt_transpose<<<dim3(32, 32), 256, 0, stream>>>(qkvb, Vt);
    attn_kernel<<<512, 256, 0, stream>>>(qkvb, Vt, attnb);
    gemm_nt<64, 0, 0, 1, 1><<<dim3(16, 32), 256, 0, stream>>>(attnb, WprojT, b_proj, x, x2, 4096, 1024, 1024);
    ln_kernel<<<4096, 256, 0, stream>>>(x2, g2, be2, h1);
    gemm_nt<128, 1, 1, 1, 0><<<dim3(32, 32), 256, 0, stream>>>(h1, W1T, b1, nullptr, ffb, 4096, 4096, 1024);
    gemm_nt<64, 0, 0, 1, 1><<<dim3(16, 32), 256, 0, stream>>>(ffb, W2T, b2, x2, out, 4096, 1024, 4096);
}

// Round 10
// 386.623 us; speedup vs baseline: 1.1470x; 1.0339x over previous
//
#include <hip/hip_runtime.h>
#include <hip/hip_bf16.h>

typedef __bf16 bf16x8 __attribute__((ext_vector_type(8)));
typedef __bf16 bf16x4 __attribute__((ext_vector_type(4)));
typedef float f32x4 __attribute__((ext_vector_type(4)));

#define T_SEQ 2048
#define EMB 1024
#define NH 16
#define DV 64

// async global->LDS, 16B per lane (wave-uniform LDS base + lane*16 layout required)
__device__ __forceinline__ void gload16(const __bf16* g, __bf16* l) {
    __builtin_amdgcn_global_load_lds(
        (const __attribute__((address_space(1))) unsigned int*)g,
        (__attribute__((address_space(3))) unsigned int*)l, 16, 0, 0);
}

// ---------------- transpose + fp32->bf16 convert (with scale) ----------------
__global__ void transpose_cvt(const float* __restrict__ src, __bf16* __restrict__ dst,
                              int R, int C, long src_bstride, long dst_bstride, float scale) {
    __shared__ float tile[32][33];
    const int b = blockIdx.z;
    const float* s = src + (long)b * src_bstride;
    __bf16* d = dst + (long)b * dst_bstride;
    const int c0 = blockIdx.x * 32, r0 = blockIdx.y * 32;
    #pragma unroll
    for (int i = threadIdx.y; i < 32; i += 8)
        tile[i][threadIdx.x] = s[(long)(r0 + i) * C + c0 + threadIdx.x];
    __syncthreads();
    #pragma unroll
    for (int i = threadIdx.y; i < 32; i += 8)
        d[(long)(c0 + i) * R + r0 + threadIdx.x] = (__bf16)(tile[threadIdx.x][i] * scale);
}

// ---------------- V transpose: qkv -> Vt[bh][64][2048] ----------------
__global__ void vt_transpose(const __bf16* __restrict__ qkv, __bf16* __restrict__ Vt) {
    __shared__ __bf16 tile[64][72];
    const int bh = blockIdx.y, b = bh >> 4, h = bh & 15;
    const int t0 = blockIdx.x * 64;
    const __bf16* src = qkv + (long)b * T_SEQ * 3072 + 2048 + h * 64;
    const int tt = threadIdx.x >> 3, seg = threadIdx.x & 7;
    #pragma unroll
    for (int half = 0; half < 2; half++) {
        const int t = half * 32 + tt;
        bf16x8 v = *reinterpret_cast<const bf16x8*>(src + (long)(t0 + t) * 3072 + seg * 8);
        *reinterpret_cast<bf16x8*>(&tile[t][seg * 8]) = v;
    }
    __syncthreads();
    __bf16* dst = Vt + (long)bh * 64 * T_SEQ + t0;
    #pragma unroll
    for (int half = 0; half < 2; half++) {
        const int d = half * 32 + tt;
        bf16x8 v;
        #pragma unroll
        for (int i = 0; i < 8; i++) v[i] = tile[seg * 8 + i][d];
        *reinterpret_cast<bf16x8*>(dst + (long)d * T_SEQ + seg * 8) = v;
    }
}

// ---------------- LayerNorm: fp32 in -> bf16 out ----------------
__global__ void ln_kernel(const float* __restrict__ x, const float* __restrict__ g,
                          const float* __restrict__ be, __bf16* __restrict__ out) {
    const int row = blockIdx.x;
    const float4 xv = reinterpret_cast<const float4*>(x + (long)row * EMB)[threadIdx.x];
    float s = xv.x + xv.y + xv.z + xv.w;
    float sq = xv.x * xv.x + xv.y * xv.y + xv.z * xv.z + xv.w * xv.w;
    #pragma unroll
    for (int off = 32; off; off >>= 1) { s += __shfl_down(s, off); sq += __shfl_down(sq, off); }
    __shared__ float red[8];
    const int w = threadIdx.x >> 6, lane = threadIdx.x & 63;
    if (lane == 0) { red[w] = s; red[4 + w] = sq; }
    __syncthreads();
    if (threadIdx.x == 0) {
        float st = red[0] + red[1] + red[2] + red[3];
        float sqt = red[4] + red[5] + red[6] + red[7];
        float mean = st * (1.0f / EMB);
        float var = sqt * (1.0f / EMB) - mean * mean;
        red[0] = mean; red[1] = rsqrtf(var + 1e-5f);
    }
    __syncthreads();
    const float mean = red[0], rstd = red[1];
    const float4 gv = reinterpret_cast<const float4*>(g)[threadIdx.x];
    const float4 bv = reinterpret_cast<const float4*>(be)[threadIdx.x];
    bf16x4 o;
    o[0] = (__bf16)((xv.x - mean) * rstd * gv.x + bv.x);
    o[1] = (__bf16)((xv.y - mean) * rstd * gv.y + bv.y);
    o[2] = (__bf16)((xv.z - mean) * rstd * gv.z + bv.z);
    o[3] = (__bf16)((xv.w - mean) * rstd * gv.w + bv.w);
    *reinterpret_cast<bf16x4*>(out + (long)row * EMB + threadIdx.x * 4) = o;
}

// ---------------- 256x256 bf16 GEMM (NT), BK=32, 3-buf counted-vmcnt pipeline ----------------
// C[M][N] = A[M][K]*BT[N][K]^T. 512 thr, 8 waves (2Mx4N), per-wave 128x64 out.
// LDS 96KB: 3 bufs x (A 256x32 + B 256x32). Swizzle: LDS chunk c of row r holds
// global chunk c ^ ((r>>1)&3); gload_lds linear dest + pre-swizzled source;
// ds_read at chunk g ^ ((rA>>1)&3) -> 2-way bank alias max (free).
// Pipeline: stage(t+2) issued at tile t start; vmcnt(4) at boundary (never 0).
template <int RELU, int HAS_BIAS>
__global__ __launch_bounds__(512)
void gemm256(const __bf16* __restrict__ A, const __bf16* __restrict__ BT,
             const float* __restrict__ bias, __bf16* __restrict__ outp,
             int M, int N, int K, int nbx) {
    __shared__ __align__(16) __bf16 lds[3][2][256 * 32];   // 96KB
    const int bid = (int)blockIdx.x;
    const int cpx = (int)gridDim.x >> 3;
    const int wg = (bid & 7) * cpx + (bid >> 3);           // XCD swizzle (nwg%8==0)
    const int bx = wg % nbx, by = wg / nbx;
    const int m0 = by * 256, n0 = bx * 256;
    const int tid = threadIdx.x, wid = tid >> 6, lane = tid & 63;
    const int wr = wid >> 2, wc = wid & 3;
    const int rA = lane & 15, g = lane >> 4, rl = g * 4;
    const int rswz = (g ^ ((rA >> 1) & 3)) * 8;            // read-side swizzled k-offset

    // staging: 512 thr cover 128 rows x 4 chunks per issue
    const int sr = tid >> 2, ch = tid & 3;
    const int sc = ch ^ ((sr >> 1) & 3);                   // source pre-swizzle
    const __bf16* Asrc = A + (long)(m0 + sr) * K + sc * 8;
    const __bf16* Bsrc = BT + (long)(n0 + sr) * K + sc * 8;
    const int dOff = sr * 32 + ch * 8;                     // linear LDS dest (base+lane*16B)

    auto stage = [&](int t) {
        const int buf = t % 3, k0 = t * 32;
        gload16(Asrc + k0,            &lds[buf][0][dOff]);
        gload16(Asrc + 128 * K + k0,  &lds[buf][0][128 * 32 + dOff]);
        gload16(Bsrc + k0,            &lds[buf][1][dOff]);
        gload16(Bsrc + 128 * K + k0,  &lds[buf][1][128 * 32 + dOff]);
    };

    f32x4 acc[8][4] = {};
    const int NT = K >> 5;
    stage(0); stage(1);
    asm volatile("s_waitcnt vmcnt(4)" ::: "memory");
    __builtin_amdgcn_s_barrier();

    for (int t = 0; t < NT; ++t) {
        const int buf = t % 3;
        if (t + 2 < NT) stage(t + 2);                      // writes buf of t-1 (freed)
        const __bf16* Abuf = lds[buf][0];
        const __bf16* Bbuf = lds[buf][1];
        bf16x8 bfr[4], af[8];
        #pragma unroll
        for (int n = 0; n < 4; n++)
            bfr[n] = *reinterpret_cast<const bf16x8*>(Bbuf + (wc * 64 + n * 16 + rA) * 32 + rswz);
        #pragma unroll
        for (int m = 0; m < 4; m++)
            af[m] = *reinterpret_cast<const bf16x8*>(Abuf + (wr * 128 + m * 16 + rA) * 32 + rswz);
        __builtin_amdgcn_s_setprio(1);
        #pragma unroll
        for (int m = 0; m < 4; m++)
            #pragma unroll
            for (int n = 0; n < 4; n++)
                acc[m][n] = __builtin_amdgcn_mfma_f32_16x16x32_bf16(af[m], bfr[n], acc[m][n], 0, 0, 0);
        __builtin_amdgcn_s_setprio(0);
        __builtin_amdgcn_s_barrier();                      // mid-tile lockstep
        #pragma unroll
        for (int m = 4; m < 8; m++)
            af[m] = *reinterpret_cast<const bf16x8*>(Abuf + (wr * 128 + m * 16 + rA) * 32 + rswz);
        __builtin_amdgcn_s_setprio(1);
        #pragma unroll
        for (int m = 4; m < 8; m++)
            #pragma unroll
            for (int n = 0; n < 4; n++)
                acc[m][n] = __builtin_amdgcn_mfma_f32_16x16x32_bf16(af[m], bfr[n], acc[m][n], 0, 0, 0);
        __builtin_amdgcn_s_setprio(0);
        asm volatile("s_waitcnt vmcnt(4)" ::: "memory");   // t+1 landed; t+2 may fly
        __builtin_amdgcn_s_barrier();
    }

    #pragma unroll
    for (int m = 0; m < 8; m++) {
        #pragma unroll
        for (int n = 0; n < 4; n++) {
            const int gc = n0 + wc * 64 + n * 16 + rA;
            float bval = 0.0f;
            if (HAS_BIAS) bval = bias[gc];
            #pragma unroll
            for (int r = 0; r < 4; r++) {
                const int gr = m0 + wr * 128 + m * 16 + rl + r;
                float v = acc[m][n][r] + bval;
                if (RELU) v = fmaxf(v, 0.0f);
                outp[(long)gr * N + gc] = (__bf16)v;
            }
        }
    }
}

// ---------------- bf16 GEMM (NT), m97 structure + T2 swizzle (proj/ffn2) ----------------
template <int BN, int OUT_BF16, int RELU, int HAS_BIAS, int HAS_RES>
__global__ __launch_bounds__(256)
void gemm_nt(const __bf16* __restrict__ A, const __bf16* __restrict__ BT,
             const float* __restrict__ bias, const float* __restrict__ res,
             void* __restrict__ outp, int M, int N, int K) {
    constexpr int NFN = BN / 32;                 // 16-wide n-frags per wave
    __shared__ __align__(16) __bf16 As[128 * 64];
    __shared__ __align__(16) __bf16 Bs[BN * 64];
    const int t = threadIdx.x;
    const int w = t >> 6, lane = t & 63;
    const int wm = (w >> 1) * 64, wn = (w & 1) * (BN / 2);
    const int m0 = blockIdx.y * 128, n0 = blockIdx.x * BN;
    const int rA = lane & 15, kA = (lane >> 4) * 8;
    const int swzr = (rA & 7) * 8;               // read-side XOR (elements)
    const int srow = t >> 3;                     // 0..31
    const int chunk = t & 7;
    const int schunk = chunk ^ (srow & 7);       // pre-swizzled source chunk

    const __bf16* Ab = A + (long)(m0 + srow) * K + schunk * 8;
    const __bf16* Bb = BT + (long)(n0 + srow) * K + schunk * 8;
    __bf16* Asw = As + srow * 64 + chunk * 8;    // linear: base + lane*16B
    __bf16* Bsw = Bs + srow * 64 + chunk * 8;

    f32x4 acc[4][NFN] = {};
    for (int k0 = 0; k0 < K; k0 += 64) {
        #pragma unroll
        for (int i = 0; i < 4; i++)
            gload16(Ab + (long)(32 * i) * K + k0, Asw + 32 * i * 64);
        #pragma unroll
        for (int i = 0; i < BN / 32; i++)
            gload16(Bb + (long)(32 * i) * K + k0, Bsw + 32 * i * 64);
        __syncthreads();   // compiler drains vmcnt before barrier
        #pragma unroll
        for (int kk = 0; kk < 2; kk++) {
            bf16x8 af[4], bfr[NFN];
            #pragma unroll
            for (int m = 0; m < 4; m++)
                af[m] = *reinterpret_cast<const bf16x8*>(
                    As + (wm + m * 16 + rA) * 64 + ((kk * 32 + kA) ^ swzr));
            #pragma unroll
            for (int n = 0; n < NFN; n++)
                bfr[n] = *reinterpret_cast<const bf16x8*>(
                    Bs + (wn + n * 16 + rA) * 64 + ((kk * 32 + kA) ^ swzr));
            #pragma unroll
            for (int m = 0; m < 4; m++)
                #pragma unroll
                for (int n = 0; n < NFN; n++)
                    acc[m][n] = __builtin_amdgcn_mfma_f32_16x16x32_bf16(af[m], bfr[n], acc[m][n], 0, 0, 0);
        }
        __syncthreads();
    }
    const int rl = (lane >> 4) * 4, cl = lane & 15;
    #pragma unroll
    for (int m = 0; m < 4; m++) {
        #pragma unroll
        for (int n = 0; n < NFN; n++) {
            const int gc = n0 + wn + n * 16 + cl;
            float bval = 0.0f;
            if (HAS_BIAS) bval = bias[gc];
            #pragma unroll
            for (int r = 0; r < 4; r++) {
                const int gr = m0 + wm + m * 16 + rl + r;
                float v = acc[m][n][r] + bval;
                if (HAS_RES) v += res[(long)gr * N + gc];
                if (RELU) v = fmaxf(v, 0.0f);
                if (OUT_BF16) ((__bf16*)outp)[(long)gr * N + gc] = (__bf16)v;
                else          ((float*)outp)[(long)gr * N + gc] = v;
            }
        }
    }
}

// ---------------- causal flash attention: LDS-staged, double-buffered ----------------
template <int MASKED>
__device__ __forceinline__ void attn_compute(
    const char* __restrict__ Kl, const char* __restrict__ Vl,
    __bf16 (*__restrict__ PsW)[72],
    const bf16x8 (&qf)[2][2], const bf16x8& ones,
    f32x4 (&o)[2][4], f32x4 (&l5)[2], float (&mr)[2][4],
    int kv0, int rA, int g, int rl, int qw)
{
    const int swz = (rA & 7) << 4;
    bf16x8 kf[4][2];
    #pragma unroll
    for (int c = 0; c < 4; c++)
        #pragma unroll
        for (int kc = 0; kc < 2; kc++)
            kf[c][kc] = *reinterpret_cast<const bf16x8*>(
                Kl + (c * 16 + rA) * 128 + ((kc * 64 + g * 16) ^ swz));
    f32x4 sa[2][4];
    __builtin_amdgcn_s_setprio(1);
    #pragma unroll
    for (int rt = 0; rt < 2; rt++)
        #pragma unroll
        for (int c = 0; c < 4; c++) {
            f32x4 acc = {};
            acc = __builtin_amdgcn_mfma_f32_16x16x32_bf16(qf[rt][0], kf[c][0], acc, 0, 0, 0);
            acc = __builtin_amdgcn_mfma_f32_16x16x32_bf16(qf[rt][1], kf[c][1], acc, 0, 0, 0);
            sa[rt][c] = acc;
        }
    __builtin_amdgcn_s_setprio(0);
    #pragma unroll
    for (int rt = 0; rt < 2; rt++) {
        #pragma unroll
        for (int r = 0; r < 4; r++) {
            float s0 = sa[rt][0][r], s1 = sa[rt][1][r], s2 = sa[rt][2][r], s3 = sa[rt][3][r];
            if (MASKED) {
                const int gr = qw + rt * 16 + rl + r;
                if (kv0 + rA > gr)      s0 = -__builtin_inff();
                if (kv0 + 16 + rA > gr) s1 = -__builtin_inff();
                if (kv0 + 32 + rA > gr) s2 = -__builtin_inff();
                if (kv0 + 48 + rA > gr) s3 = -__builtin_inff();
            }
            float tm = fmaxf(fmaxf(s0, s1), fmaxf(s2, s3));
            #pragma unroll
            for (int msk = 1; msk < 16; msk <<= 1) tm = fmaxf(tm, __shfl_xor(tm, msk));
            const float mo = mr[rt][r];
            // T13 defer-max: skip O-rescale while max growth <= 8 (P bounded by e^8)
            float mu = mo;
            if (__any(tm > mo + 8.0f)) {
                const float mn = fmaxf(mo, tm);
                mr[rt][r] = mn;
                const float sc = __expf(mo - mn);
                #pragma unroll
                for (int n = 0; n < 4; n++) o[rt][n][r] *= sc;
                l5[rt][r] *= sc;
                mu = mn;
            }
            const float p0 = __expf(s0 - mu);
            const float p1 = __expf(s1 - mu);
            const float p2 = __expf(s2 - mu);
            const float p3 = __expf(s3 - mu);
            const int prow = rt * 16 + rl + r;
            PsW[prow][rA]      = (__bf16)p0;
            PsW[prow][16 + rA] = (__bf16)p1;
            PsW[prow][32 + rA] = (__bf16)p2;
            PsW[prow][48 + rA] = (__bf16)p3;
        }
    }
    asm volatile("s_waitcnt lgkmcnt(0)" ::: "memory");

    bf16x8 ap[2][2];
    #pragma unroll
    for (int rt = 0; rt < 2; rt++)
        #pragma unroll
        for (int ks = 0; ks < 2; ks++)
            ap[rt][ks] = *reinterpret_cast<const bf16x8*>(&PsW[rt * 16 + rA][ks * 32 + g * 8]);
    __builtin_amdgcn_s_setprio(1);
    #pragma unroll
    for (int ks = 0; ks < 2; ks++) {
        #pragma unroll
        for (int rt = 0; rt < 2; rt++)
            l5[rt] = __builtin_amdgcn_mfma_f32_16x16x32_bf16(ap[rt][ks], ones, l5[rt], 0, 0, 0);
        #pragma unroll
        for (int n = 0; n < 4; n++) {
            bf16x8 bv = *reinterpret_cast<const bf16x8*>(
                Vl + (n * 16 + rA) * 128 + ((ks * 64 + g * 16) ^ swz));
            #pragma unroll
            for (int rt = 0; rt < 2; rt++)
                o[rt][n] = __builtin_amdgcn_mfma_f32_16x16x32_bf16(ap[rt][ks], bv, o[rt][n], 0, 0, 0);
        }
    }
    __builtin_amdgcn_s_setprio(0);
}

// grid: 512 blocks. XCD-confined heads (4/XCD) + complementary heavy/light pairing.
__global__ __launch_bounds__(256)
void attn_kernel(const __bf16* __restrict__ qkv, const __bf16* __restrict__ Vt,
                 __bf16* __restrict__ attn) {
    __shared__ __bf16 Ks[2][64 * 64];
    __shared__ __bf16 Vs[2][64 * 64];
    __shared__ __bf16 Ps[4][32][72];

    const int bid = (int)blockIdx.x;
    const int xcd = bid & 7, s = bid >> 3;          // dispatch: round-robin XCDs
    const int slot = s >> 5, c = s & 31;
    const int bh = xcd * 4 + slot * 2 + (c >> 4);
    const int t16 = c & 15;
    const int qtile = slot ? t16 : 15 - t16;        // desc then asc: CU pair sums const
    const int b = bh >> 4, h = bh & 15;
    const int q0 = qtile * 128;
    const int w = threadIdx.x >> 6, lane = threadIdx.x & 63;
    const int qw = q0 + w * 32;
    const int rA = lane & 15, g = lane >> 4, rl = g * 4;
    const int srow8 = lane >> 3;
    const int scol = (lane & 7) * 16;
    const int wcol = scol ^ (srow8 << 4);

    const char* qb = (const char*)(qkv + (long)b * T_SEQ * 3072 + h * 64);
    const char* kb = qb + 2048;
    const char* vtb = (const char*)(Vt + (long)bh * 64 * T_SEQ);

    bf16x8 qf[2][2];
    #pragma unroll
    for (int rt = 0; rt < 2; rt++)
        #pragma unroll
        for (int kc = 0; kc < 2; kc++)
            qf[rt][kc] = *reinterpret_cast<const bf16x8*>(
                qb + (long)(qw + rt * 16 + rA) * 6144 + kc * 64 + g * 16);

    bf16x8 ones;
    #pragma unroll
    for (int i = 0; i < 8; i++) ones[i] = (__bf16)1.0f;

    f32x4 o[2][4] = {};
    f32x4 l5[2] = {};
    float mr[2][4];
    #pragma unroll
    for (int rt = 0; rt < 2; rt++)
        #pragma unroll
        for (int r = 0; r < 4; r++) mr[rt][r] = -__builtin_inff();

    const int nsteps = q0 / 64 + 2;
    const int t_avail = qw + 32;
    const int isK = (w < 2);
    const int r0 = (w & 1) * 32 + srow8;

    bf16x8 stg[4];
    auto issue = [&](int kv0) {
        if (isK) {
            #pragma unroll
            for (int i = 0; i < 4; i++)
                stg[i] = *reinterpret_cast<const bf16x8*>(kb + (long)(kv0 + r0 + i * 8) * 6144 + scol);
        } else {
            #pragma unroll
            for (int i = 0; i < 4; i++)
                stg[i] = *reinterpret_cast<const bf16x8*>(vtb + (long)(r0 + i * 8) * 4096 + kv0 * 2 + scol);
        }
    };
    auto lwrite = [&](int buf) {
        char* base = isK ? (char*)Ks[buf] : (char*)Vs[buf];
        #pragma unroll
        for (int i = 0; i < 4; i++)
            *reinterpret_cast<bf16x8*>(base + (r0 + i * 8) * 128 + wcol) = stg[i];
    };

    issue(0);
    lwrite(0);
    __syncthreads();

    for (int t = 0; t < nsteps; ++t) {
        const int kv0 = t * 64, cur = t & 1;
        const bool has_next = (t + 1 < nsteps);
        if (has_next) issue(kv0 + 64);
        if (kv0 < t_avail) {
            if (kv0 + 64 <= qw)
                attn_compute<0>((const char*)Ks[cur], (const char*)Vs[cur], Ps[w],
                                qf, ones, o, l5, mr, kv0, rA, g, rl, qw);
            else
                attn_compute<1>((const char*)Ks[cur], (const char*)Vs[cur], Ps[w],
                                qf, ones, o, l5, mr, kv0, rA, g, rl, qw);
        }
        if (has_next) lwrite(cur ^ 1);
        __syncthreads();
    }

    #pragma unroll
    for (int rt = 0; rt < 2; rt++)
        #pragma unroll
        for (int n = 0; n < 4; n++)
            #pragma unroll
            for (int r = 0; r < 4; r++) {
                const int gr = qw + rt * 16 + rl + r;
                attn[(long)(b * T_SEQ + gr) * EMB + h * 64 + n * 16 + rA] =
                    (__bf16)(o[rt][n][r] / l5[rt][r]);
            }
}

// ---------------- launch ----------------
extern "C" void kernel_launch(void* const* d_in, const int* in_sizes, int n_in,
                              void* d_out, int out_size, void* d_ws, size_t ws_size,
                              hipStream_t stream) {
    const float* x      = (const float*)d_in[0];
    const float* wq     = (const float*)d_in[1];
    const float* wk     = (const float*)d_in[2];
    const float* wv     = (const float*)d_in[3];
    const float* w_proj = (const float*)d_in[4];
    const float* b_proj = (const float*)d_in[5];
    const float* w1     = (const float*)d_in[6];
    const float* b1     = (const float*)d_in[7];
    const float* w2     = (const float*)d_in[8];
    const float* b2     = (const float*)d_in[9];
    const float* g1     = (const float*)d_in[10];
    const float* be1    = (const float*)d_in[11];
    const float* g2     = (const float*)d_in[12];
    const float* be2    = (const float*)d_in[13];
    float* out = (float*)d_out;

    char* ws = (char*)d_ws;
    __bf16* WqkvT = (__bf16*)ws;  ws += 3072L * 1024 * 2;
    __bf16* WprojT = (__bf16*)ws; ws += 1024L * 1024 * 2;
    __bf16* W1T = (__bf16*)ws;    ws += 4096L * 1024 * 2;
    __bf16* W2T = (__bf16*)ws;    ws += 1024L * 4096 * 2;
    __bf16* h1  = (__bf16*)ws;    ws += 4096L * 1024 * 2;
    __bf16* qkvb = (__bf16*)ws;
    __bf16* attnb = (__bf16*)(ws + 4096L * 3072 * 2);
    __bf16* ffb = (__bf16*)ws;    ws += 4096L * 3072 * 2 + 4096L * 1024 * 2;
    float* x2 = (float*)ws;
    __bf16* Vt = (__bf16*)ws;   // overlays x2 (dead before proj-GEMM writes x2)

    const dim3 tb(32, 8);
    transpose_cvt<<<dim3(2, 32, 16), tb, 0, stream>>>(wq, WqkvT,                1024, 64, 65536L, 65536L, 0.03125f);
    transpose_cvt<<<dim3(2, 32, 16), tb, 0, stream>>>(wk, WqkvT + 1024L * 1024, 1024, 64, 65536L, 65536L, 1.0f);
    transpose_cvt<<<dim3(2, 32, 16), tb, 0, stream>>>(wv, WqkvT + 2048L * 1024, 1024, 64, 65536L, 65536L, 1.0f);
    transpose_cvt<<<dim3(32, 32, 1),  tb, 0, stream>>>(w_proj, WprojT, 1024, 1024, 0, 0, 1.0f);
    transpose_cvt<<<dim3(128, 32, 1), tb, 0, stream>>>(w1, W1T, 1024, 4096, 0, 0, 1.0f);
    transpose_cvt<<<dim3(32, 128, 1), tb, 0, stream>>>(w2, W2T, 4096, 1024, 0, 0, 1.0f);

    ln_kernel<<<4096, 256, 0, stream>>>(x, g1, be1, h1);
    gemm256<0, 0><<<192, 512, 0, stream>>>(h1, WqkvT, nullptr, qkvb, 4096, 3072, 1024, 12);
    vt_transpose<<<dim3(32, 32), 256, 0, stream>>>(qkvb, Vt);
    attn_kernel<<<512, 256, 0, stream>>>(qkvb, Vt, attnb);
    gemm_nt<64, 0, 0, 1, 1><<<dim3(16, 32), 256, 0, stream>>>(attnb, WprojT, b_proj, x, x2, 4096, 1024, 1024);
    ln_kernel<<<4096, 256, 0, stream>>>(x2, g2, be2, h1);
    gemm256<1, 1><<<256, 512, 0, stream>>>(h1, W1T, b1, ffb, 4096, 4096, 1024, 16);
    gemm_nt<64, 0, 0, 1, 1><<<dim3(16, 32), 256, 0, stream>>>(ffb, W2T, b2, x2, out, 4096, 1024, 4096);
}

// Round 11
// 377.277 us; speedup vs baseline: 1.1754x; 1.0248x over previous
//
#include <hip/hip_runtime.h>
#include <hip/hip_bf16.h>

typedef __bf16 bf16x8 __attribute__((ext_vector_type(8)));
typedef __bf16 bf16x4 __attribute__((ext_vector_type(4)));
typedef float f32x4 __attribute__((ext_vector_type(4)));

#define T_SEQ 2048
#define EMB 1024
#define NH 16
#define DV 64

// async global->LDS, 16B per lane (wave-uniform LDS base + lane*16 layout required)
__device__ __forceinline__ void gload16(const __bf16* g, __bf16* l) {
    __builtin_amdgcn_global_load_lds(
        (const __attribute__((address_space(1))) unsigned int*)g,
        (__attribute__((address_space(3))) unsigned int*)l, 16, 0, 0);
}

// ---------------- transpose + fp32->bf16 convert (with scale) ----------------
__global__ void transpose_cvt(const float* __restrict__ src, __bf16* __restrict__ dst,
                              int R, int C, long src_bstride, long dst_bstride, float scale) {
    __shared__ float tile[32][33];
    const int b = blockIdx.z;
    const float* s = src + (long)b * src_bstride;
    __bf16* d = dst + (long)b * dst_bstride;
    const int c0 = blockIdx.x * 32, r0 = blockIdx.y * 32;
    #pragma unroll
    for (int i = threadIdx.y; i < 32; i += 8)
        tile[i][threadIdx.x] = s[(long)(r0 + i) * C + c0 + threadIdx.x];
    __syncthreads();
    #pragma unroll
    for (int i = threadIdx.y; i < 32; i += 8)
        d[(long)(c0 + i) * R + r0 + threadIdx.x] = (__bf16)(tile[threadIdx.x][i] * scale);
}

// ---------------- V transpose: qkv -> Vt[bh][64][2048] ----------------
__global__ void vt_transpose(const __bf16* __restrict__ qkv, __bf16* __restrict__ Vt) {
    __shared__ __bf16 tile[64][72];
    const int bh = blockIdx.y, b = bh >> 4, h = bh & 15;
    const int t0 = blockIdx.x * 64;
    const __bf16* src = qkv + (long)b * T_SEQ * 3072 + 2048 + h * 64;
    const int tt = threadIdx.x >> 3, seg = threadIdx.x & 7;
    #pragma unroll
    for (int half = 0; half < 2; half++) {
        const int t = half * 32 + tt;
        bf16x8 v = *reinterpret_cast<const bf16x8*>(src + (long)(t0 + t) * 3072 + seg * 8);
        *reinterpret_cast<bf16x8*>(&tile[t][seg * 8]) = v;
    }
    __syncthreads();
    __bf16* dst = Vt + (long)bh * 64 * T_SEQ + t0;
    #pragma unroll
    for (int half = 0; half < 2; half++) {
        const int d = half * 32 + tt;
        bf16x8 v;
        #pragma unroll
        for (int i = 0; i < 8; i++) v[i] = tile[seg * 8 + i][d];
        *reinterpret_cast<bf16x8*>(dst + (long)d * T_SEQ + seg * 8) = v;
    }
}

// ---------------- LayerNorm: fp32 in -> bf16 out ----------------
__global__ void ln_kernel(const float* __restrict__ x, const float* __restrict__ g,
                          const float* __restrict__ be, __bf16* __restrict__ out) {
    const int row = blockIdx.x;
    const float4 xv = reinterpret_cast<const float4*>(x + (long)row * EMB)[threadIdx.x];
    float s = xv.x + xv.y + xv.z + xv.w;
    float sq = xv.x * xv.x + xv.y * xv.y + xv.z * xv.z + xv.w * xv.w;
    #pragma unroll
    for (int off = 32; off; off >>= 1) { s += __shfl_down(s, off); sq += __shfl_down(sq, off); }
    __shared__ float red[8];
    const int w = threadIdx.x >> 6, lane = threadIdx.x & 63;
    if (lane == 0) { red[w] = s; red[4 + w] = sq; }
    __syncthreads();
    if (threadIdx.x == 0) {
        float st = red[0] + red[1] + red[2] + red[3];
        float sqt = red[4] + red[5] + red[6] + red[7];
        float mean = st * (1.0f / EMB);
        float var = sqt * (1.0f / EMB) - mean * mean;
        red[0] = mean; red[1] = rsqrtf(var + 1e-5f);
    }
    __syncthreads();
    const float mean = red[0], rstd = red[1];
    const float4 gv = reinterpret_cast<const float4*>(g)[threadIdx.x];
    const float4 bv = reinterpret_cast<const float4*>(be)[threadIdx.x];
    bf16x4 o;
    o[0] = (__bf16)((xv.x - mean) * rstd * gv.x + bv.x);
    o[1] = (__bf16)((xv.y - mean) * rstd * gv.y + bv.y);
    o[2] = (__bf16)((xv.z - mean) * rstd * gv.z + bv.z);
    o[3] = (__bf16)((xv.w - mean) * rstd * gv.w + bv.w);
    *reinterpret_cast<bf16x4*>(out + (long)row * EMB + threadIdx.x * 4) = o;
}

// ---------------- 256x256 bf16 GEMM (NT), BK=32, 3-buf counted-vmcnt pipeline ----------------
template <int RELU, int HAS_BIAS>
__global__ __launch_bounds__(512)
void gemm256(const __bf16* __restrict__ A, const __bf16* __restrict__ BT,
             const float* __restrict__ bias, __bf16* __restrict__ outp,
             int M, int N, int K, int nbx) {
    __shared__ __align__(16) __bf16 lds[3][2][256 * 32];   // 96KB
    const int bid = (int)blockIdx.x;
    const int cpx = (int)gridDim.x >> 3;
    const int wg = (bid & 7) * cpx + (bid >> 3);           // XCD swizzle (nwg%8==0)
    const int bx = wg % nbx, by = wg / nbx;
    const int m0 = by * 256, n0 = bx * 256;
    const int tid = threadIdx.x, wid = tid >> 6, lane = tid & 63;
    const int wr = wid >> 2, wc = wid & 3;
    const int rA = lane & 15, g = lane >> 4, rl = g * 4;
    const int rswz = (g ^ ((rA >> 1) & 3)) * 8;            // read-side swizzled k-offset

    const int sr = tid >> 2, ch = tid & 3;
    const int sc = ch ^ ((sr >> 1) & 3);                   // source pre-swizzle
    const __bf16* Asrc = A + (long)(m0 + sr) * K + sc * 8;
    const __bf16* Bsrc = BT + (long)(n0 + sr) * K + sc * 8;
    const int dOff = sr * 32 + ch * 8;                     // linear LDS dest (base+lane*16B)

    auto stage = [&](int t) {
        const int buf = t % 3, k0 = t * 32;
        gload16(Asrc + k0,            &lds[buf][0][dOff]);
        gload16(Asrc + 128 * K + k0,  &lds[buf][0][128 * 32 + dOff]);
        gload16(Bsrc + k0,            &lds[buf][1][dOff]);
        gload16(Bsrc + 128 * K + k0,  &lds[buf][1][128 * 32 + dOff]);
    };

    f32x4 acc[8][4] = {};
    const int NT = K >> 5;
    stage(0); stage(1);
    asm volatile("s_waitcnt vmcnt(4)" ::: "memory");
    __builtin_amdgcn_s_barrier();

    for (int t = 0; t < NT; ++t) {
        const int buf = t % 3;
        if (t + 2 < NT) stage(t + 2);                      // writes buf of t-1 (freed)
        const __bf16* Abuf = lds[buf][0];
        const __bf16* Bbuf = lds[buf][1];
        bf16x8 bfr[4], af[8];
        #pragma unroll
        for (int n = 0; n < 4; n++)
            bfr[n] = *reinterpret_cast<const bf16x8*>(Bbuf + (wc * 64 + n * 16 + rA) * 32 + rswz);
        #pragma unroll
        for (int m = 0; m < 4; m++)
            af[m] = *reinterpret_cast<const bf16x8*>(Abuf + (wr * 128 + m * 16 + rA) * 32 + rswz);
        __builtin_amdgcn_s_setprio(1);
        #pragma unroll
        for (int m = 0; m < 4; m++)
            #pragma unroll
            for (int n = 0; n < 4; n++)
                acc[m][n] = __builtin_amdgcn_mfma_f32_16x16x32_bf16(af[m], bfr[n], acc[m][n], 0, 0, 0);
        __builtin_amdgcn_s_setprio(0);
        __builtin_amdgcn_s_barrier();                      // mid-tile lockstep
        #pragma unroll
        for (int m = 4; m < 8; m++)
            af[m] = *reinterpret_cast<const bf16x8*>(Abuf + (wr * 128 + m * 16 + rA) * 32 + rswz);
        __builtin_amdgcn_s_setprio(1);
        #pragma unroll
        for (int m = 4; m < 8; m++)
            #pragma unroll
            for (int n = 0; n < 4; n++)
                acc[m][n] = __builtin_amdgcn_mfma_f32_16x16x32_bf16(af[m], bfr[n], acc[m][n], 0, 0, 0);
        __builtin_amdgcn_s_setprio(0);
        // counted wait mid-loop; full drain in the last 2 iters (next tile has no
        // trailing stage to push it out — guarantees t+1's loads landed)
        if (t + 3 < NT) asm volatile("s_waitcnt vmcnt(4)" ::: "memory");
        else            asm volatile("s_waitcnt vmcnt(0)" ::: "memory");
        __builtin_amdgcn_s_barrier();
    }

    #pragma unroll
    for (int m = 0; m < 8; m++) {
        #pragma unroll
        for (int n = 0; n < 4; n++) {
            const int gc = n0 + wc * 64 + n * 16 + rA;
            float bval = 0.0f;
            if (HAS_BIAS) bval = bias[gc];
            #pragma unroll
            for (int r = 0; r < 4; r++) {
                const int gr = m0 + wr * 128 + m * 16 + rl + r;
                float v = acc[m][n][r] + bval;
                if (RELU) v = fmaxf(v, 0.0f);
                outp[(long)gr * N + gc] = (__bf16)v;
            }
        }
    }
}

// ---------------- 128x128 bf16 GEMM (NT), BK=32, 3-buf counted-vmcnt pipeline ----------------
// fp32 out = A*BT^T + bias + res. 256 thr, 4 waves (2Mx2N), per-wave 64x64 out.
// LDS 48KB (3 bufs). Same swizzle/pipeline discipline as gemm256.
__global__ __launch_bounds__(256)
void gemm128p(const __bf16* __restrict__ A, const __bf16* __restrict__ BT,
              const float* __restrict__ bias, const float* __restrict__ res,
              float* __restrict__ outp, int M, int N, int K, int nbx) {
    __shared__ __align__(16) __bf16 lds[3][2][128 * 32];   // 48KB
    const int bid = (int)blockIdx.x;
    const int cpx = (int)gridDim.x >> 3;
    const int wg = (bid & 7) * cpx + (bid >> 3);           // XCD swizzle (nwg%8==0)
    const int bx = wg % nbx, by = wg / nbx;
    const int m0 = by * 128, n0 = bx * 128;
    const int tid = threadIdx.x, wid = tid >> 6, lane = tid & 63;
    const int wr = wid >> 1, wc = wid & 1;
    const int rA = lane & 15, g = lane >> 4, rl = g * 4;
    const int rswz = (g ^ ((rA >> 1) & 3)) * 8;

    const int sr = tid >> 2, ch = tid & 3;                 // 64 rows x 4 chunks
    const int sc = ch ^ ((sr >> 1) & 3);                   // (row+64 has same swizzle: 64%8==0)
    const __bf16* Asrc = A + (long)(m0 + sr) * K + sc * 8;
    const __bf16* Bsrc = BT + (long)(n0 + sr) * K + sc * 8;
    const int dOff = sr * 32 + ch * 8;

    auto stage = [&](int t) {
        const int buf = t % 3, k0 = t * 32;
        gload16(Asrc + k0,           &lds[buf][0][dOff]);
        gload16(Asrc + 64 * (long)K + k0, &lds[buf][0][64 * 32 + dOff]);
        gload16(Bsrc + k0,           &lds[buf][1][dOff]);
        gload16(Bsrc + 64 * (long)K + k0, &lds[buf][1][64 * 32 + dOff]);
    };

    f32x4 acc[4][4] = {};
    const int NT = K >> 5;
    stage(0); stage(1);
    asm volatile("s_waitcnt vmcnt(4)" ::: "memory");
    __builtin_amdgcn_s_barrier();

    for (int t = 0; t < NT; ++t) {
        const int buf = t % 3;
        if (t + 2 < NT) stage(t + 2);
        const __bf16* Abuf = lds[buf][0];
        const __bf16* Bbuf = lds[buf][1];
        bf16x8 af[4], bfr[4];
        #pragma unroll
        for (int n = 0; n < 4; n++)
            bfr[n] = *reinterpret_cast<const bf16x8*>(Bbuf + (wc * 64 + n * 16 + rA) * 32 + rswz);
        #pragma unroll
        for (int m = 0; m < 4; m++)
            af[m] = *reinterpret_cast<const bf16x8*>(Abuf + (wr * 64 + m * 16 + rA) * 32 + rswz);
        __builtin_amdgcn_s_setprio(1);
        #pragma unroll
        for (int m = 0; m < 4; m++)
            #pragma unroll
            for (int n = 0; n < 4; n++)
                acc[m][n] = __builtin_amdgcn_mfma_f32_16x16x32_bf16(af[m], bfr[n], acc[m][n], 0, 0, 0);
        __builtin_amdgcn_s_setprio(0);
        if (t + 3 < NT) asm volatile("s_waitcnt vmcnt(4)" ::: "memory");
        else            asm volatile("s_waitcnt vmcnt(0)" ::: "memory");
        __builtin_amdgcn_s_barrier();
    }

    #pragma unroll
    for (int m = 0; m < 4; m++) {
        #pragma unroll
        for (int n = 0; n < 4; n++) {
            const int gc = n0 + wc * 64 + n * 16 + rA;
            const float bval = bias[gc];
            #pragma unroll
            for (int r = 0; r < 4; r++) {
                const int gr = m0 + wr * 64 + m * 16 + rl + r;
                outp[(long)gr * N + gc] = acc[m][n][r] + bval + res[(long)gr * N + gc];
            }
        }
    }
}

// ---------------- causal flash attention: LDS-staged, double-buffered ----------------
template <int MASKED>
__device__ __forceinline__ void attn_compute(
    const char* __restrict__ Kl, const char* __restrict__ Vl,
    __bf16 (*__restrict__ PsW)[72],
    const bf16x8 (&qf)[2][2], const bf16x8& ones,
    f32x4 (&o)[2][4], f32x4 (&l5)[2], float (&mr)[2][4],
    int kv0, int rA, int g, int rl, int qw)
{
    const int swz = (rA & 7) << 4;
    bf16x8 kf[4][2];
    #pragma unroll
    for (int c = 0; c < 4; c++)
        #pragma unroll
        for (int kc = 0; kc < 2; kc++)
            kf[c][kc] = *reinterpret_cast<const bf16x8*>(
                Kl + (c * 16 + rA) * 128 + ((kc * 64 + g * 16) ^ swz));
    f32x4 sa[2][4];
    __builtin_amdgcn_s_setprio(1);
    #pragma unroll
    for (int rt = 0; rt < 2; rt++)
        #pragma unroll
        for (int c = 0; c < 4; c++) {
            f32x4 acc = {};
            acc = __builtin_amdgcn_mfma_f32_16x16x32_bf16(qf[rt][0], kf[c][0], acc, 0, 0, 0);
            acc = __builtin_amdgcn_mfma_f32_16x16x32_bf16(qf[rt][1], kf[c][1], acc, 0, 0, 0);
            sa[rt][c] = acc;
        }
    __builtin_amdgcn_s_setprio(0);
    #pragma unroll
    for (int rt = 0; rt < 2; rt++) {
        #pragma unroll
        for (int r = 0; r < 4; r++) {
            float s0 = sa[rt][0][r], s1 = sa[rt][1][r], s2 = sa[rt][2][r], s3 = sa[rt][3][r];
            if (MASKED) {
                const int gr = qw + rt * 16 + rl + r;
                if (kv0 + rA > gr)      s0 = -__builtin_inff();
                if (kv0 + 16 + rA > gr) s1 = -__builtin_inff();
                if (kv0 + 32 + rA > gr) s2 = -__builtin_inff();
                if (kv0 + 48 + rA > gr) s3 = -__builtin_inff();
            }
            float tm = fmaxf(fmaxf(s0, s1), fmaxf(s2, s3));
            #pragma unroll
            for (int msk = 1; msk < 16; msk <<= 1) tm = fmaxf(tm, __shfl_xor(tm, msk));
            const float mo = mr[rt][r];
            // T13 defer-max: skip O-rescale while max growth <= 8 (P bounded by e^8)
            float mu = mo;
            if (__any(tm > mo + 8.0f)) {
                const float mn = fmaxf(mo, tm);
                mr[rt][r] = mn;
                const float sc = __expf(mo - mn);
                #pragma unroll
                for (int n = 0; n < 4; n++) o[rt][n][r] *= sc;
                l5[rt][r] *= sc;
                mu = mn;
            }
            const float p0 = __expf(s0 - mu);
            const float p1 = __expf(s1 - mu);
            const float p2 = __expf(s2 - mu);
            const float p3 = __expf(s3 - mu);
            const int prow = rt * 16 + rl + r;
            PsW[prow][rA]      = (__bf16)p0;
            PsW[prow][16 + rA] = (__bf16)p1;
            PsW[prow][32 + rA] = (__bf16)p2;
            PsW[prow][48 + rA] = (__bf16)p3;
        }
    }
    asm volatile("s_waitcnt lgkmcnt(0)" ::: "memory");

    bf16x8 ap[2][2];
    #pragma unroll
    for (int rt = 0; rt < 2; rt++)
        #pragma unroll
        for (int ks = 0; ks < 2; ks++)
            ap[rt][ks] = *reinterpret_cast<const bf16x8*>(&PsW[rt * 16 + rA][ks * 32 + g * 8]);
    __builtin_amdgcn_s_setprio(1);
    #pragma unroll
    for (int ks = 0; ks < 2; ks++) {
        #pragma unroll
        for (int rt = 0; rt < 2; rt++)
            l5[rt] = __builtin_amdgcn_mfma_f32_16x16x32_bf16(ap[rt][ks], ones, l5[rt], 0, 0, 0);
        #pragma unroll
        for (int n = 0; n < 4; n++) {
            bf16x8 bv = *reinterpret_cast<const bf16x8*>(
                Vl + (n * 16 + rA) * 128 + ((ks * 64 + g * 16) ^ swz));
            #pragma unroll
            for (int rt = 0; rt < 2; rt++)
                o[rt][n] = __builtin_amdgcn_mfma_f32_16x16x32_bf16(ap[rt][ks], bv, o[rt][n], 0, 0, 0);
        }
    }
    __builtin_amdgcn_s_setprio(0);
}

// grid: 512 blocks. XCD-confined heads (4/XCD) + complementary heavy/light pairing.
__global__ __launch_bounds__(256)
void attn_kernel(const __bf16* __restrict__ qkv, const __bf16* __restrict__ Vt,
                 __bf16* __restrict__ attn) {
    __shared__ __bf16 Ks[2][64 * 64];
    __shared__ __bf16 Vs[2][64 * 64];
    __shared__ __bf16 Ps[4][32][72];

    const int bid = (int)blockIdx.x;
    const int xcd = bid & 7, s = bid >> 3;          // dispatch: round-robin XCDs
    const int slot = s >> 5, c = s & 31;
    const int bh = xcd * 4 + slot * 2 + (c >> 4);
    const int t16 = c & 15;
    const int qtile = slot ? t16 : 15 - t16;        // desc then asc: CU pair sums const
    const int b = bh >> 4, h = bh & 15;
    const int q0 = qtile * 128;
    const int w = threadIdx.x >> 6, lane = threadIdx.x & 63;
    const int qw = q0 + w * 32;
    const int rA = lane & 15, g = lane >> 4, rl = g * 4;
    const int srow8 = lane >> 3;
    const int scol = (lane & 7) * 16;
    const int wcol = scol ^ (srow8 << 4);

    const char* qb = (const char*)(qkv + (long)b * T_SEQ * 3072 + h * 64);
    const char* kb = qb + 2048;
    const char* vtb = (const char*)(Vt + (long)bh * 64 * T_SEQ);

    bf16x8 qf[2][2];
    #pragma unroll
    for (int rt = 0; rt < 2; rt++)
        #pragma unroll
        for (int kc = 0; kc < 2; kc++)
            qf[rt][kc] = *reinterpret_cast<const bf16x8*>(
                qb + (long)(qw + rt * 16 + rA) * 6144 + kc * 64 + g * 16);

    bf16x8 ones;
    #pragma unroll
    for (int i = 0; i < 8; i++) ones[i] = (__bf16)1.0f;

    f32x4 o[2][4] = {};
    f32x4 l5[2] = {};
    float mr[2][4];
    #pragma unroll
    for (int rt = 0; rt < 2; rt++)
        #pragma unroll
        for (int r = 0; r < 4; r++) mr[rt][r] = -__builtin_inff();

    const int nsteps = q0 / 64 + 2;
    const int t_avail = qw + 32;
    const int isK = (w < 2);
    const int r0 = (w & 1) * 32 + srow8;

    bf16x8 stg[4];
    auto issue = [&](int kv0) {
        if (isK) {
            #pragma unroll
            for (int i = 0; i < 4; i++)
                stg[i] = *reinterpret_cast<const bf16x8*>(kb + (long)(kv0 + r0 + i * 8) * 6144 + scol);
        } else {
            #pragma unroll
            for (int i = 0; i < 4; i++)
                stg[i] = *reinterpret_cast<const bf16x8*>(vtb + (long)(r0 + i * 8) * 4096 + kv0 * 2 + scol);
        }
    };
    auto lwrite = [&](int buf) {
        char* base = isK ? (char*)Ks[buf] : (char*)Vs[buf];
        #pragma unroll
        for (int i = 0; i < 4; i++)
            *reinterpret_cast<bf16x8*>(base + (r0 + i * 8) * 128 + wcol) = stg[i];
    };

    issue(0);
    lwrite(0);
    __syncthreads();

    for (int t = 0; t < nsteps; ++t) {
        const int kv0 = t * 64, cur = t & 1;
        const bool has_next = (t + 1 < nsteps);
        if (has_next) issue(kv0 + 64);
        if (kv0 < t_avail) {
            if (kv0 + 64 <= qw)
                attn_compute<0>((const char*)Ks[cur], (const char*)Vs[cur], Ps[w],
                                qf, ones, o, l5, mr, kv0, rA, g, rl, qw);
            else
                attn_compute<1>((const char*)Ks[cur], (const char*)Vs[cur], Ps[w],
                                qf, ones, o, l5, mr, kv0, rA, g, rl, qw);
        }
        if (has_next) lwrite(cur ^ 1);
        __syncthreads();
    }

    #pragma unroll
    for (int rt = 0; rt < 2; rt++)
        #pragma unroll
        for (int n = 0; n < 4; n++)
            #pragma unroll
            for (int r = 0; r < 4; r++) {
                const int gr = qw + rt * 16 + rl + r;
                attn[(long)(b * T_SEQ + gr) * EMB + h * 64 + n * 16 + rA] =
                    (__bf16)(o[rt][n][r] / l5[rt][r]);
            }
}

// ---------------- launch ----------------
extern "C" void kernel_launch(void* const* d_in, const int* in_sizes, int n_in,
                              void* d_out, int out_size, void* d_ws, size_t ws_size,
                              hipStream_t stream) {
    const float* x      = (const float*)d_in[0];
    const float* wq     = (const float*)d_in[1];
    const float* wk     = (const float*)d_in[2];
    const float* wv     = (const float*)d_in[3];
    const float* w_proj = (const float*)d_in[4];
    const float* b_proj = (const float*)d_in[5];
    const float* w1     = (const float*)d_in[6];
    const float* b1     = (const float*)d_in[7];
    const float* w2     = (const float*)d_in[8];
    const float* b2     = (const float*)d_in[9];
    const float* g1     = (const float*)d_in[10];
    const float* be1    = (const float*)d_in[11];
    const float* g2     = (const float*)d_in[12];
    const float* be2    = (const float*)d_in[13];
    float* out = (float*)d_out;

    char* ws = (char*)d_ws;
    __bf16* WqkvT = (__bf16*)ws;  ws += 3072L * 1024 * 2;
    __bf16* WprojT = (__bf16*)ws; ws += 1024L * 1024 * 2;
    __bf16* W1T = (__bf16*)ws;    ws += 4096L * 1024 * 2;
    __bf16* W2T = (__bf16*)ws;    ws += 1024L * 4096 * 2;
    __bf16* h1  = (__bf16*)ws;    ws += 4096L * 1024 * 2;
    __bf16* qkvb = (__bf16*)ws;
    __bf16* attnb = (__bf16*)(ws + 4096L * 3072 * 2);
    __bf16* ffb = (__bf16*)ws;    ws += 4096L * 3072 * 2 + 4096L * 1024 * 2;
    float* x2 = (float*)ws;
    __bf16* Vt = (__bf16*)ws;   // overlays x2 (dead before proj-GEMM writes x2)

    const dim3 tb(32, 8);
    transpose_cvt<<<dim3(2, 32, 16), tb, 0, stream>>>(wq, WqkvT,                1024, 64, 65536L, 65536L, 0.03125f);
    transpose_cvt<<<dim3(2, 32, 16), tb, 0, stream>>>(wk, WqkvT + 1024L * 1024, 1024, 64, 65536L, 65536L, 1.0f);
    transpose_cvt<<<dim3(2, 32, 16), tb, 0, stream>>>(wv, WqkvT + 2048L * 1024, 1024, 64, 65536L, 65536L, 1.0f);
    transpose_cvt<<<dim3(32, 32, 1),  tb, 0, stream>>>(w_proj, WprojT, 1024, 1024, 0, 0, 1.0f);
    transpose_cvt<<<dim3(128, 32, 1), tb, 0, stream>>>(w1, W1T, 1024, 4096, 0, 0, 1.0f);
    transpose_cvt<<<dim3(32, 128, 1), tb, 0, stream>>>(w2, W2T, 4096, 1024, 0, 0, 1.0f);

    ln_kernel<<<4096, 256, 0, stream>>>(x, g1, be1, h1);
    gemm256<0, 0><<<192, 512, 0, stream>>>(h1, WqkvT, nullptr, qkvb, 4096, 3072, 1024, 12);
    vt_transpose<<<dim3(32, 32), 256, 0, stream>>>(qkvb, Vt);
    attn_kernel<<<512, 256, 0, stream>>>(qkvb, Vt, attnb);
    gemm128p<<<256, 256, 0, stream>>>(attnb, WprojT, b_proj, x, x2, 4096, 1024, 1024, 8);
    ln_kernel<<<4096, 256, 0, stream>>>(x2, g2, be2, h1);
    gemm256<1, 1><<<256, 512, 0, stream>>>(h1, W1T, b1, ffb, 4096, 4096, 1024, 16);
    gemm128p<<<256, 256, 0, stream>>>(ffb, W2T, b2, x2, out, 4096, 1024, 4096, 8);
}